// Round 1
// baseline (1797.368 us; speedup 1.0000x reference)
//
#include <hip/hip_runtime.h>
#include <cstdint>
#include <cstddef>

#define H     1024
#define LSEQ  2048
#define NHH   4
#define DKK   128
#define DVV   256
#define KDIM  512
#define VDIM  1024
#define GRR   64
#define MTOT  4096   // B*L

enum { ASRC_PLAIN = 0, ASRC_LERPX = 1 };
enum { EPI_NONE = 0, EPI_TANH = 1, EPI_LERP = 2, EPI_DEC = 3 };

// C[m][n] = sum_k A[m][acol+k] * B[n][bcol+k]   (BT layout: both K-contiguous)
// BM=BN=64, BK=16, 256 threads, 4x4 register tile per thread.
template<int ASRC, int EPI>
__global__ __launch_bounds__(256) void gemm_bt(
    const float* __restrict__ A, int lda, int acol,
    const float* __restrict__ B, int ldb, int bcol,
    float* __restrict__ C, int ldc,
    int M, int N, int K,
    const float* __restrict__ xsrc,   // LERPX staging / LERP epilogue (ld = H)
    const float* __restrict__ mux,    // LERPX
    const float* __restrict__ bias)   // LERP: x_bias row; DEC: bw2
{
    __shared__ float As[16][64];
    __shared__ float Bs[16][64];
    const int m0 = blockIdx.x * 64;
    const int n0 = blockIdx.y * 64;
    const int t  = threadIdx.x;
    const int tx = t & 15, ty = t >> 4;
    const int sm = t >> 2;          // staging row 0..63
    const int sq = (t & 3) * 4;     // staging k-quad

    float acc[4][4];
#pragma unroll
    for (int i = 0; i < 4; i++)
#pragma unroll
        for (int j = 0; j < 4; j++) acc[i][j] = 0.f;

    for (int k0 = 0; k0 < K; k0 += 16) {
        {   // stage A (M always multiple of 64 -> no guard)
            const int m = m0 + sm;
            float4 av;
            if constexpr (ASRC == ASRC_PLAIN) {
                av = *(const float4*)(A + (size_t)m * lda + acol + k0 + sq);
            } else {
                const float4 xv = *(const float4*)(xsrc + (size_t)m * lda + k0 + sq);
                float4 pv = make_float4(0.f, 0.f, 0.f, 0.f);
                if ((m & (LSEQ - 1)) != 0)
                    pv = *(const float4*)(xsrc + (size_t)(m - 1) * lda + k0 + sq);
                const float4 mv = *(const float4*)(mux + k0 + sq);
                av.x = xv.x + (pv.x - xv.x) * mv.x;
                av.y = xv.y + (pv.y - xv.y) * mv.y;
                av.z = xv.z + (pv.z - xv.z) * mv.z;
                av.w = xv.w + (pv.w - xv.w) * mv.w;
            }
            As[sq + 0][sm] = av.x; As[sq + 1][sm] = av.y;
            As[sq + 2][sm] = av.z; As[sq + 3][sm] = av.w;
        }
        {   // stage B with N guard (N=160 case)
            const int n = n0 + sm;
            float4 bv = make_float4(0.f, 0.f, 0.f, 0.f);
            if (n < N) bv = *(const float4*)(B + (size_t)n * ldb + bcol + k0 + sq);
            Bs[sq + 0][sm] = bv.x; Bs[sq + 1][sm] = bv.y;
            Bs[sq + 2][sm] = bv.z; Bs[sq + 3][sm] = bv.w;
        }
        __syncthreads();
#pragma unroll
        for (int kk = 0; kk < 16; kk++) {
            const float4 a = *(const float4*)&As[kk][ty * 4];
            const float4 b = *(const float4*)&Bs[kk][tx * 4];
            const float av2[4] = {a.x, a.y, a.z, a.w};
            const float bv2[4] = {b.x, b.y, b.z, b.w};
#pragma unroll
            for (int i = 0; i < 4; i++)
#pragma unroll
                for (int j = 0; j < 4; j++) acc[i][j] += av2[i] * bv2[j];
        }
        __syncthreads();
    }

    const int nbase = n0 + tx * 4;
    if (nbase >= N) return;
#pragma unroll
    for (int i = 0; i < 4; i++) {
        const int m = m0 + ty * 4 + i;
        float4 r = make_float4(acc[i][0], acc[i][1], acc[i][2], acc[i][3]);
        if constexpr (EPI == EPI_TANH) {
            r.x = tanhf(r.x); r.y = tanhf(r.y); r.z = tanhf(r.z); r.w = tanhf(r.w);
        } else if constexpr (EPI == EPI_DEC) {
            const float4 bb = *(const float4*)(bias + nbase);
            r.x = expf(-expf(r.x + bb.x));
            r.y = expf(-expf(r.y + bb.y));
            r.z = expf(-expf(r.z + bb.z));
            r.w = expf(-expf(r.w + bb.w));
        } else if constexpr (EPI == EPI_LERP) {
            const float4 bb = *(const float4*)(bias + nbase);
            const float4 xv = *(const float4*)(xsrc + (size_t)m * H + nbase);
            float4 pv = make_float4(0.f, 0.f, 0.f, 0.f);
            if ((m & (LSEQ - 1)) != 0)
                pv = *(const float4*)(xsrc + (size_t)(m - 1) * H + nbase);
            r.x = xv.x + (pv.x - xv.x) * (r.x + bb.x);
            r.y = xv.y + (pv.y - xv.y) * (r.y + bb.y);
            r.z = xv.z + (pv.z - xv.z) * (r.z + bb.z);
            r.w = xv.w + (pv.w - xv.w) * (r.w + bb.w);
        }
        *(float4*)(C + (size_t)m * ldc + nbase) = r;
    }
}

// RWKV-6 scan. 64 blocks = (b,h,vchunk of 32). 256 threads: kg = t&7 (16 k each),
// vl = t>>3 (one v). State S[kg*16+i][v] in 16 registers. dec = exp(w) precomputed.
__global__ __launch_bounds__(256) void scan_kernel(
    const float* __restrict__ r, const float* __restrict__ k,
    const float* __restrict__ v, const float* __restrict__ dec,
    const float* __restrict__ bonus, float* __restrict__ o)
{
    const int vc = blockIdx.x & 7;
    const int bh = blockIdx.x >> 3;
    const int b  = bh >> 2;
    const int h  = bh & 3;
    const int t  = threadIdx.x;
    const int vl = t >> 3;
    const int kg = t & 7;

    __shared__ float rbuf[8][128], kbuf[8][128], dbuf[8][128], vbuf[8][32];

    float S[16], u[16];
#pragma unroll
    for (int i = 0; i < 16; i++) { S[i] = 0.f; u[i] = bonus[h * DKK + kg * 16 + i]; }

    const size_t rkbase = (size_t)b * LSEQ * KDIM + (size_t)h * DKK;
    const size_t vbase  = (size_t)b * LSEQ * VDIM + (size_t)h * DVV + (size_t)vc * 32;

    for (int t0 = 0; t0 < LSEQ; t0 += 8) {
        __syncthreads();
        for (int idx = t; idx < 1024; idx += 256) {
            const int s = idx >> 7, kk = idx & 127;
            const size_t off = rkbase + (size_t)(t0 + s) * KDIM + kk;
            rbuf[s][kk] = r[off];
            kbuf[s][kk] = k[off];
            dbuf[s][kk] = dec[off];
        }
        {
            const int s = t >> 5, vv = t & 31;
            vbuf[s][vv] = v[vbase + (size_t)(t0 + s) * VDIM + vv];
        }
        __syncthreads();
        for (int s = 0; s < 8; s++) {
            const float vv = vbuf[s][vl];
            float part = 0.f;
#pragma unroll
            for (int q = 0; q < 4; q++) {
                const float4 rr = *(const float4*)&rbuf[s][kg * 16 + q * 4];
                const float4 kk = *(const float4*)&kbuf[s][kg * 16 + q * 4];
                const float4 dd = *(const float4*)&dbuf[s][kg * 16 + q * 4];
                float kv;
                kv = kk.x * vv; part += rr.x * (S[q*4+0] + u[q*4+0] * kv); S[q*4+0] = dd.x * S[q*4+0] + kv;
                kv = kk.y * vv; part += rr.y * (S[q*4+1] + u[q*4+1] * kv); S[q*4+1] = dd.y * S[q*4+1] + kv;
                kv = kk.z * vv; part += rr.z * (S[q*4+2] + u[q*4+2] * kv); S[q*4+2] = dd.z * S[q*4+2] + kv;
                kv = kk.w * vv; part += rr.w * (S[q*4+3] + u[q*4+3] * kv); S[q*4+3] = dd.w * S[q*4+3] + kv;
            }
            part += __shfl_xor(part, 1);
            part += __shfl_xor(part, 2);
            part += __shfl_xor(part, 4);
            if (kg == 0)
                o[(size_t)(b * LSEQ + t0 + s) * VDIM + h * DVV + vc * 32 + vl] = part;
        }
    }
}

// Per-head LayerNorm (biased var) + swish gate. One wave per (m,h).
__global__ __launch_bounds__(256) void ln_gate_kernel(
    const float* __restrict__ o, const float* __restrict__ g,
    const float* __restrict__ lnw, const float* __restrict__ lnb,
    float* __restrict__ out)
{
    const int m    = blockIdx.x;
    const int t    = threadIdx.x;
    const int h    = t >> 6;
    const int lane = t & 63;
    const size_t base = (size_t)m * VDIM + (size_t)h * DVV + lane * 4;
    const float4 ov = *(const float4*)(o + base);
    float sum = ov.x + ov.y + ov.z + ov.w;
    float sq  = ov.x * ov.x + ov.y * ov.y + ov.z * ov.z + ov.w * ov.w;
#pragma unroll
    for (int off = 1; off < 64; off <<= 1) {
        sum += __shfl_xor(sum, off);
        sq  += __shfl_xor(sq, off);
    }
    const float mean = sum * (1.f / DVV);
    const float var  = sq * (1.f / DVV) - mean * mean;
    const float rstd = rsqrtf(var + 1e-5f);
    const float4 gv = *(const float4*)(g + base);
    const float4 wv = *(const float4*)(lnw + lane * 4);
    const float4 bv = *(const float4*)(lnb + lane * 4);
    float4 res;
    res.x = ((ov.x - mean) * rstd * wv.x + bv.x) * (gv.x / (1.f + expf(-gv.x)));
    res.y = ((ov.y - mean) * rstd * wv.y + bv.y) * (gv.y / (1.f + expf(-gv.y)));
    res.z = ((ov.z - mean) * rstd * wv.z + bv.z) * (gv.z / (1.f + expf(-gv.z)));
    res.w = ((ov.w - mean) * rstd * wv.w + bv.w) * (gv.w / (1.f + expf(-gv.w)));
    *(float4*)(out + base) = res;
}

extern "C" void kernel_launch(void* const* d_in, const int* in_sizes, int n_in,
                              void* d_out, int out_size, void* d_ws, size_t ws_size,
                              hipStream_t stream)
{
    const float* x     = (const float*)d_in[0];
    const float* mu_x  = (const float*)d_in[1];
    const float* Wx1   = (const float*)d_in[2];
    const float* Wx2   = (const float*)d_in[3];
    const float* xb    = (const float*)d_in[4];
    const float* Wr    = (const float*)d_in[5];
    const float* Wk    = (const float*)d_in[6];
    const float* Wv    = (const float*)d_in[7];
    const float* Wg    = (const float*)d_in[8];
    const float* Ww1   = (const float*)d_in[9];
    const float* Ww2   = (const float*)d_in[10];
    const float* bw2   = (const float*)d_in[11];
    const float* bonus = (const float*)d_in[12];
    const float* lnw   = (const float*)d_in[13];
    const float* lnb   = (const float*)d_in[14];
    const float* Wo    = (const float*)d_in[15];
    float* out = (float*)d_out;

    float* ws   = (float*)d_ws;
    float* xp   = ws;                               // 4096*160
    float* ins  = ws + 655360;                      // 5 * 4096*1024
    float* rb   = ins + 5ul * 4194304;              // 4096*512
    float* kb   = rb + 2097152;
    float* vb   = kb + 2097152;                     // 4096*1024
    float* gb   = vb + 4194304;                     // 4096*1024
    float* wlow = gb + 4194304;                     // 4096*64
    float* dec  = wlow + 262144;                    // 4096*512
    float* o    = ins;                              // alias in_0 (consumed by r-GEMM)
    float* gated = ins + 4194304;                   // alias in_1 (consumed by w-GEMM)
    (void)in_sizes; (void)n_in; (void)out_size; (void)ws_size;

    dim3 blk(256);

    // xp = tanh(lerp(x, mu_x) @ Wx1^T)
    gemm_bt<ASRC_LERPX, EPI_TANH><<<dim3(64, 3), blk, 0, stream>>>(
        x, H, 0, Wx1, H, 0, xp, 160, MTOT, 160, H, x, mu_x, nullptr);

    // in_n = x + delta * (xp_n @ Wx2_n^T + x_bias_n),  n = r,w,k,v,g
    for (int n = 0; n < 5; n++)
        gemm_bt<ASRC_PLAIN, EPI_LERP><<<dim3(64, 16), blk, 0, stream>>>(
            xp, 160, n * 32, Wx2, 160, n * 32, ins + (size_t)n * 4194304, H,
            MTOT, H, 32, x, nullptr, xb + n * H);

    // projections
    gemm_bt<ASRC_PLAIN, EPI_NONE><<<dim3(64, 8), blk, 0, stream>>>(
        ins + 0ul * 4194304, H, 0, Wr, H, 0, rb, KDIM, MTOT, KDIM, H, nullptr, nullptr, nullptr);
    gemm_bt<ASRC_PLAIN, EPI_NONE><<<dim3(64, 8), blk, 0, stream>>>(
        ins + 2ul * 4194304, H, 0, Wk, H, 0, kb, KDIM, MTOT, KDIM, H, nullptr, nullptr, nullptr);
    gemm_bt<ASRC_PLAIN, EPI_NONE><<<dim3(64, 16), blk, 0, stream>>>(
        ins + 3ul * 4194304, H, 0, Wv, H, 0, vb, VDIM, MTOT, VDIM, H, nullptr, nullptr, nullptr);
    gemm_bt<ASRC_PLAIN, EPI_NONE><<<dim3(64, 16), blk, 0, stream>>>(
        ins + 4ul * 4194304, H, 0, Wg, H, 0, gb, VDIM, MTOT, VDIM, H, nullptr, nullptr, nullptr);
    gemm_bt<ASRC_PLAIN, EPI_TANH><<<dim3(64, 1), blk, 0, stream>>>(
        ins + 1ul * 4194304, H, 0, Ww1, H, 0, wlow, GRR, MTOT, GRR, H, nullptr, nullptr, nullptr);

    // dec = exp(-exp(wlow @ Ww2^T + bw2))  (= exp(w_t), the state decay)
    gemm_bt<ASRC_PLAIN, EPI_DEC><<<dim3(64, 8), blk, 0, stream>>>(
        wlow, GRR, 0, Ww2, GRR, 0, dec, KDIM, MTOT, KDIM, GRR, nullptr, nullptr, bw2);

    // sequential RWKV scan -> o[b,l,h,v] (writes over consumed in_0 region)
    scan_kernel<<<dim3(64), blk, 0, stream>>>(rb, kb, vb, dec, bonus, o);

    // per-head LN + swish gate (writes over consumed in_1 region)
    ln_gate_kernel<<<dim3(4096), blk, 0, stream>>>(o, gb, lnw, lnb, gated);

    // out = gated @ Wo^T
    gemm_bt<ASRC_PLAIN, EPI_NONE><<<dim3(64, 16), blk, 0, stream>>>(
        gated, VDIM, 0, Wo, VDIM, 0, out, H, MTOT, H, VDIM, nullptr, nullptr, nullptr);
}

// Round 3
// 959.737 us; speedup vs baseline: 1.8728x; 1.8728x over previous
//
#include <hip/hip_runtime.h>
#include <cstdint>
#include <cstddef>

#define H     1024
#define LSEQ  2048
#define NHH   4
#define DKK   128
#define DVV   256
#define KDIM  512
#define VDIM  1024
#define GRR   64
#define MTOT  4096   // B*L

enum { ASRC_PLAIN = 0, ASRC_LERPX = 1 };
enum { EPI_NONE = 0, EPI_TANH = 1, EPI_LERP = 2, EPI_DEC = 3 };

typedef __attribute__((ext_vector_type(8))) _Float16 half8;
typedef __attribute__((ext_vector_type(4))) float f32x4;

static __device__ __forceinline__ unsigned short f2h(float f) {
    _Float16 h = (_Float16)f;          // v_cvt_f16_f32, RNE
    union { _Float16 h; unsigned short u; } c;
    c.h = h;
    return c.u;
}

// ---------------------------------------------------------------------------
// f32 VALU GEMM (small/awkward shapes): C[m][n] = sum_k A[m][k+acol]*B[n][k+bcol]
// ---------------------------------------------------------------------------
template<int ASRC, int EPI>
__global__ __launch_bounds__(256) void gemm_bt(
    const float* __restrict__ A, int lda, int acol,
    const float* __restrict__ B, int ldb, int bcol,
    float* __restrict__ Cf, unsigned short* __restrict__ C2, int ldc,
    int M, int N, int K,
    const float* __restrict__ xsrc,   // LERPX staging / LERP epilogue (ld = H)
    const float* __restrict__ mux,    // LERPX
    const float* __restrict__ bias)   // LERP: x_bias row; DEC: bw2
{
    __shared__ float As[16][64];
    __shared__ float Bs[16][64];
    const int m0 = blockIdx.x * 64;
    const int n0 = blockIdx.y * 64;
    const int t  = threadIdx.x;
    const int tx = t & 15, ty = t >> 4;
    const int sm = t >> 2;          // staging row 0..63
    const int sq = (t & 3) * 4;     // staging k-quad

    float acc[4][4];
#pragma unroll
    for (int i = 0; i < 4; i++)
#pragma unroll
        for (int j = 0; j < 4; j++) acc[i][j] = 0.f;

    for (int k0 = 0; k0 < K; k0 += 16) {
        {   // stage A (M always multiple of 64 -> no guard)
            const int m = m0 + sm;
            float4 av;
            if constexpr (ASRC == ASRC_PLAIN) {
                av = *(const float4*)(A + (size_t)m * lda + acol + k0 + sq);
            } else {
                const float4 xv = *(const float4*)(xsrc + (size_t)m * lda + k0 + sq);
                float4 pv = make_float4(0.f, 0.f, 0.f, 0.f);
                if ((m & (LSEQ - 1)) != 0)
                    pv = *(const float4*)(xsrc + (size_t)(m - 1) * lda + k0 + sq);
                const float4 mv = *(const float4*)(mux + k0 + sq);
                av.x = xv.x + (pv.x - xv.x) * mv.x;
                av.y = xv.y + (pv.y - xv.y) * mv.y;
                av.z = xv.z + (pv.z - xv.z) * mv.z;
                av.w = xv.w + (pv.w - xv.w) * mv.w;
            }
            As[sq + 0][sm] = av.x; As[sq + 1][sm] = av.y;
            As[sq + 2][sm] = av.z; As[sq + 3][sm] = av.w;
        }
        {   // stage B with N guard (N=160 case)
            const int n = n0 + sm;
            float4 bv = make_float4(0.f, 0.f, 0.f, 0.f);
            if (n < N) bv = *(const float4*)(B + (size_t)n * ldb + bcol + k0 + sq);
            Bs[sq + 0][sm] = bv.x; Bs[sq + 1][sm] = bv.y;
            Bs[sq + 2][sm] = bv.z; Bs[sq + 3][sm] = bv.w;
        }
        __syncthreads();
#pragma unroll
        for (int kk = 0; kk < 16; kk++) {
            const float4 a = *(const float4*)&As[kk][ty * 4];
            const float4 b = *(const float4*)&Bs[kk][tx * 4];
            const float av2[4] = {a.x, a.y, a.z, a.w};
            const float bv2[4] = {b.x, b.y, b.z, b.w};
#pragma unroll
            for (int i = 0; i < 4; i++)
#pragma unroll
                for (int j = 0; j < 4; j++) acc[i][j] += av2[i] * bv2[j];
        }
        __syncthreads();
    }

    const int nbase = n0 + tx * 4;
    if (nbase >= N) return;
#pragma unroll
    for (int i = 0; i < 4; i++) {
        const int m = m0 + ty * 4 + i;
        float4 r = make_float4(acc[i][0], acc[i][1], acc[i][2], acc[i][3]);
        if constexpr (EPI == EPI_TANH) {
            r.x = tanhf(r.x); r.y = tanhf(r.y); r.z = tanhf(r.z); r.w = tanhf(r.w);
        } else if constexpr (EPI == EPI_DEC) {
            const float4 bb = *(const float4*)(bias + nbase);
            r.x = expf(-expf(r.x + bb.x));
            r.y = expf(-expf(r.y + bb.y));
            r.z = expf(-expf(r.z + bb.z));
            r.w = expf(-expf(r.w + bb.w));
        } else if constexpr (EPI == EPI_LERP) {
            const float4 bb = *(const float4*)(bias + nbase);
            const float4 xv = *(const float4*)(xsrc + (size_t)m * H + nbase);
            float4 pv = make_float4(0.f, 0.f, 0.f, 0.f);
            if ((m & (LSEQ - 1)) != 0)
                pv = *(const float4*)(xsrc + (size_t)(m - 1) * H + nbase);
            r.x = xv.x + (pv.x - xv.x) * (r.x + bb.x);
            r.y = xv.y + (pv.y - xv.y) * (r.y + bb.y);
            r.z = xv.z + (pv.z - xv.z) * (r.z + bb.z);
            r.w = xv.w + (pv.w - xv.w) * (r.w + bb.w);
        }
        if (Cf) *(float4*)(Cf + (size_t)m * ldc + nbase) = r;
        if (C2) {
            ushort4 p;
            p.x = f2h(r.x); p.y = f2h(r.y); p.z = f2h(r.z); p.w = f2h(r.w);
            *(ushort4*)(C2 + (size_t)m * ldc + nbase) = p;
        }
    }
}

// ---------------------------------------------------------------------------
// fp16 MFMA GEMM (m97 structure): C[m][n] = sum_k A[m][k] * B[n][k], f32 out.
// 128x128 tile, BK=32, 256 threads (4 waves, each a 64x64 quadrant),
// global_load_lds width 16, 16x16x32 f16 MFMA.
// M, N multiples of 128; K multiple of 32.
// ---------------------------------------------------------------------------
__global__ __launch_bounds__(256) void gemm_mfma_bt(
    const unsigned short* __restrict__ A, int lda,
    const unsigned short* __restrict__ B, int ldb,
    float* __restrict__ C, int ldc, int K)
{
    __shared__ __align__(16) unsigned short As[128 * 32];
    __shared__ __align__(16) unsigned short Bs[128 * 32];
    const int t    = threadIdx.x;
    const int w    = t >> 6;
    const int lane = t & 63;
    const int m0 = blockIdx.x * 128;
    const int n0 = blockIdx.y * 128;
    const int mw = (w & 1) * 64;
    const int nw = (w >> 1) * 64;
    const int l15 = lane & 15;
    const int q4  = lane >> 4;

    f32x4 acc[4][4];
#pragma unroll
    for (int i = 0; i < 4; i++)
#pragma unroll
        for (int j = 0; j < 4; j++) {
            f32x4 z = {0.f, 0.f, 0.f, 0.f};
            acc[i][j] = z;
        }

    for (int k0 = 0; k0 < K; k0 += 32) {
        __syncthreads();   // previous-iter LDS readers done
#pragma unroll
        for (int jj = 0; jj < 2; jj++) {
            const int c   = w * 128 + jj * 64 + lane;   // 16B chunk id
            const int row = c >> 2;
            const int col = (c & 3) * 8;
            __builtin_amdgcn_global_load_lds(
                (const __attribute__((address_space(1))) void*)(A + (size_t)(m0 + row) * lda + k0 + col),
                (__attribute__((address_space(3))) void*)((char*)As + (w * 128 + jj * 64) * 16),
                16, 0, 0);
            __builtin_amdgcn_global_load_lds(
                (const __attribute__((address_space(1))) void*)(B + (size_t)(n0 + row) * ldb + k0 + col),
                (__attribute__((address_space(3))) void*)((char*)Bs + (w * 128 + jj * 64) * 16),
                16, 0, 0);
        }
        __syncthreads();   // drain global_load_lds

        half8 a[4], b[4];
#pragma unroll
        for (int i = 0; i < 4; i++)
            a[i] = *(const half8*)(As + (mw + i * 16 + l15) * 32 + q4 * 8);
#pragma unroll
        for (int j = 0; j < 4; j++)
            b[j] = *(const half8*)(Bs + (nw + j * 16 + l15) * 32 + q4 * 8);
#pragma unroll
        for (int i = 0; i < 4; i++)
#pragma unroll
            for (int j = 0; j < 4; j++)
                acc[i][j] = __builtin_amdgcn_mfma_f32_16x16x32_f16(a[i], b[j], acc[i][j], 0, 0, 0);
    }

#pragma unroll
    for (int i = 0; i < 4; i++) {
        const int m_base = m0 + mw + i * 16 + q4 * 4;
#pragma unroll
        for (int j = 0; j < 4; j++) {
            const int n = n0 + nw + j * 16 + l15;
#pragma unroll
            for (int r = 0; r < 4; r++)
                C[(size_t)(m_base + r) * ldc + n] = acc[i][j][r];
        }
    }
}

// ---------------------------------------------------------------------------
// Weight f32 -> fp16 pack (Wr|Wk|Wv|Wg|Wo -> one contiguous buffer)
// ---------------------------------------------------------------------------
__global__ __launch_bounds__(256) void cvt_weights(
    const float* __restrict__ Wr, const float* __restrict__ Wk,
    const float* __restrict__ Wv, const float* __restrict__ Wg,
    const float* __restrict__ Wo, unsigned short* __restrict__ out)
{
    const int i4 = (blockIdx.x * 256 + threadIdx.x) * 4;
    const float* src; int off;
    if      (i4 <  524288) { src = Wr; off = i4; }
    else if (i4 < 1048576) { src = Wk; off = i4 -  524288; }
    else if (i4 < 2097152) { src = Wv; off = i4 - 1048576; }
    else if (i4 < 3145728) { src = Wg; off = i4 - 2097152; }
    else                   { src = Wo; off = i4 - 3145728; }
    const float4 v = *(const float4*)(src + off);
    ushort4 o4;
    o4.x = f2h(v.x); o4.y = f2h(v.y); o4.z = f2h(v.z); o4.w = f2h(v.w);
    *(ushort4*)(out + i4) = o4;
}

// ---------------------------------------------------------------------------
// RWKV-6 scan. 256 blocks = (b, h, vchunk of 8). 256 threads = 32 kquad x 8 v.
// Thread owns k = kg*4..kg*4+3 for one v; state in 4 regs; conflict-free LDS;
// register-staged global prefetch hides HBM latency behind the 8-step chunk.
// ---------------------------------------------------------------------------
__global__ __launch_bounds__(256) void scan_kernel(
    const float* __restrict__ r, const float* __restrict__ k,
    const float* __restrict__ v, const float* __restrict__ dec,
    const float* __restrict__ bonus, float* __restrict__ o)
{
    const int vc = blockIdx.x & 31;
    const int bh = blockIdx.x >> 5;
    const int b  = bh >> 2;
    const int h  = bh & 3;
    const int t  = threadIdx.x;
    const int kg = t & 31;
    const int vl = t >> 5;

    __shared__ float rbuf[8][128], kbuf[8][128], dbuf[8][128], vbuf[8][8];

    float S[4] = {0.f, 0.f, 0.f, 0.f}, u[4];
#pragma unroll
    for (int j = 0; j < 4; j++) u[j] = bonus[h * DKK + kg * 4 + j];

    const int sr = t >> 5, sq = t & 31;       // r/k/dec staging: row sr, quad sq
    const int sv = t >> 3, vv8 = t & 7;       // v staging (t < 64)
    const size_t rkoff0 = (size_t)b * LSEQ * KDIM + h * DKK + sq * 4;
    const size_t voff0  = (size_t)b * LSEQ * VDIM + h * DVV + vc * 8 + vv8;
    const size_t obase  = (size_t)b * LSEQ * VDIM + h * DVV + vc * 8 + vl;

    float4 pr, pk, pd; float pv = 0.f;
    {
        const size_t off = rkoff0 + (size_t)sr * KDIM;
        pr = *(const float4*)(r + off);
        pk = *(const float4*)(k + off);
        pd = *(const float4*)(dec + off);
        if (t < 64) pv = v[voff0 + (size_t)sv * VDIM];
    }

    for (int t0 = 0; t0 < LSEQ; t0 += 8) {
        *(float4*)&rbuf[sr][sq * 4] = pr;
        *(float4*)&kbuf[sr][sq * 4] = pk;
        *(float4*)&dbuf[sr][sq * 4] = pd;
        if (t < 64) vbuf[sv][vv8] = pv;
        __syncthreads();
        if (t0 + 8 < LSEQ) {
            const size_t off = rkoff0 + (size_t)(t0 + 8 + sr) * KDIM;
            pr = *(const float4*)(r + off);
            pk = *(const float4*)(k + off);
            pd = *(const float4*)(dec + off);
            if (t < 64) pv = v[voff0 + (size_t)(t0 + 8 + sv) * VDIM];
        }
#pragma unroll
        for (int s = 0; s < 8; s++) {
            const float vv = vbuf[s][vl];
            const float4 rr = *(const float4*)&rbuf[s][kg * 4];
            const float4 kk = *(const float4*)&kbuf[s][kg * 4];
            const float4 dd = *(const float4*)&dbuf[s][kg * 4];
            float part, kv;
            kv = kk.x * vv; part  = rr.x * (S[0] + u[0] * kv); S[0] = dd.x * S[0] + kv;
            kv = kk.y * vv; part += rr.y * (S[1] + u[1] * kv); S[1] = dd.y * S[1] + kv;
            kv = kk.z * vv; part += rr.z * (S[2] + u[2] * kv); S[2] = dd.z * S[2] + kv;
            kv = kk.w * vv; part += rr.w * (S[3] + u[3] * kv); S[3] = dd.w * S[3] + kv;
            part += __shfl_xor(part, 1);
            part += __shfl_xor(part, 2);
            part += __shfl_xor(part, 4);
            part += __shfl_xor(part, 8);
            part += __shfl_xor(part, 16);
            if (kg == 0) o[obase + (size_t)(t0 + s) * VDIM] = part;
        }
        __syncthreads();
    }
}

// ---------------------------------------------------------------------------
// Per-head LayerNorm (biased var) + swish gate -> fp16. One wave per (m,h).
// ---------------------------------------------------------------------------
__global__ __launch_bounds__(256) void ln_gate_kernel(
    const float* __restrict__ o, const float* __restrict__ g,
    const float* __restrict__ lnw, const float* __restrict__ lnb,
    unsigned short* __restrict__ out)
{
    const int m    = blockIdx.x;
    const int t    = threadIdx.x;
    const int h    = t >> 6;
    const int lane = t & 63;
    const size_t base = (size_t)m * VDIM + (size_t)h * DVV + lane * 4;
    const float4 ov = *(const float4*)(o + base);
    float sum = ov.x + ov.y + ov.z + ov.w;
    float sq  = ov.x * ov.x + ov.y * ov.y + ov.z * ov.z + ov.w * ov.w;
#pragma unroll
    for (int off = 1; off < 64; off <<= 1) {
        sum += __shfl_xor(sum, off);
        sq  += __shfl_xor(sq, off);
    }
    const float mean = sum * (1.f / DVV);
    const float var  = sq * (1.f / DVV) - mean * mean;
    const float rstd = rsqrtf(var + 1e-5f);
    const float4 gv = *(const float4*)(g + base);
    const float4 wv = *(const float4*)(lnw + lane * 4);
    const float4 bv = *(const float4*)(lnb + lane * 4);
    float4 res;
    res.x = ((ov.x - mean) * rstd * wv.x + bv.x) * (gv.x / (1.f + expf(-gv.x)));
    res.y = ((ov.y - mean) * rstd * wv.y + bv.y) * (gv.y / (1.f + expf(-gv.y)));
    res.z = ((ov.z - mean) * rstd * wv.z + bv.z) * (gv.z / (1.f + expf(-gv.z)));
    res.w = ((ov.w - mean) * rstd * wv.w + bv.w) * (gv.w / (1.f + expf(-gv.w)));
    ushort4 p;
    p.x = f2h(res.x); p.y = f2h(res.y); p.z = f2h(res.z); p.w = f2h(res.w);
    *(ushort4*)(out + base) = p;
}

extern "C" void kernel_launch(void* const* d_in, const int* in_sizes, int n_in,
                              void* d_out, int out_size, void* d_ws, size_t ws_size,
                              hipStream_t stream)
{
    const float* x     = (const float*)d_in[0];
    const float* mu_x  = (const float*)d_in[1];
    const float* Wx1   = (const float*)d_in[2];
    const float* Wx2   = (const float*)d_in[3];
    const float* xb    = (const float*)d_in[4];
    const float* Wr    = (const float*)d_in[5];
    const float* Wk    = (const float*)d_in[6];
    const float* Wv    = (const float*)d_in[7];
    const float* Wg    = (const float*)d_in[8];
    const float* Ww1   = (const float*)d_in[9];
    const float* Ww2   = (const float*)d_in[10];
    const float* bw2   = (const float*)d_in[11];
    const float* bonus = (const float*)d_in[12];
    const float* lnw   = (const float*)d_in[13];
    const float* lnb   = (const float*)d_in[14];
    const float* Wo    = (const float*)d_in[15];
    float* out = (float*)d_out;
    (void)in_sizes; (void)n_in; (void)out_size; (void)ws_size;

    float* ws = (float*)d_ws;
    // f32 regions
    float* xp    = ws;                          // 655360
    float* in_w  = ws + 655360;                 // 4194304  (w-branch lerp, f32)
    float* insbf = ws + 4849664;                // 8388608 f32-slots = 4 fp16 bufs
    float* rb    = ws + 13238272;               // 2097152
    float* kb    = ws + 15335424;               // 2097152
    float* vb    = ws + 17432576;               // 4194304
    float* gb    = ws + 21626880;               // 4194304
    float* wlow  = ws + 25821184;               // 262144
    float* dec   = ws + 26083328;               // 2097152
    float* wbf   = ws + 28180480;               // 2097152 f32-slots = 4194304 fp16
    // fp16 views
    unsigned short* insb   = (unsigned short*)insbf;      // 4 x 4194304
    unsigned short* Wb     = (unsigned short*)wbf;
    unsigned short* Wrb    = Wb;
    unsigned short* Wkb    = Wb +  524288;
    unsigned short* Wvb    = Wb + 1048576;
    unsigned short* Wgb    = Wb + 2097152;
    unsigned short* Wob    = Wb + 3145728;
    // aliases over consumed regions
    float*          o      = insbf;                       // over insb slots 0,1
    unsigned short* gatedb = insb + 2ul * 4194304;        // over insb slot 2 (v)

    dim3 blk(256);

    cvt_weights<<<dim3(4096), blk, 0, stream>>>(Wr, Wk, Wv, Wg, Wo, Wb);

    // xp = tanh(lerp(x, mu_x) @ Wx1^T)
    gemm_bt<ASRC_LERPX, EPI_TANH><<<dim3(64, 3), blk, 0, stream>>>(
        x, H, 0, Wx1, H, 0, xp, nullptr, 160, MTOT, 160, H, x, mu_x, nullptr);

    // in_n = x + delta * (xp_n @ Wx2_n^T + x_bias_n)  -> fp16 (w-branch: f32)
    for (int n = 0; n < 5; n++) {
        float*          Cf = (n == 1) ? in_w : nullptr;
        unsigned short* C2 = (n == 1) ? nullptr : insb + (size_t)(n == 0 ? 0 : n - 1) * 4194304;
        gemm_bt<ASRC_PLAIN, EPI_LERP><<<dim3(64, 16), blk, 0, stream>>>(
            xp, 160, n * 32, Wx2, 160, n * 32, Cf, C2, H,
            MTOT, H, 32, x, nullptr, xb + n * H);
    }

    // w LoRA (f32): wlow = tanh(in_w @ Ww1^T);  dec = exp(-exp(wlow @ Ww2^T + bw2))
    gemm_bt<ASRC_PLAIN, EPI_TANH><<<dim3(64, 1), blk, 0, stream>>>(
        in_w, H, 0, Ww1, H, 0, wlow, nullptr, GRR, MTOT, GRR, H, nullptr, nullptr, nullptr);
    gemm_bt<ASRC_PLAIN, EPI_DEC><<<dim3(64, 8), blk, 0, stream>>>(
        wlow, GRR, 0, Ww2, GRR, 0, dec, nullptr, KDIM, MTOT, KDIM, GRR, nullptr, nullptr, bw2);

    // big projections: fp16 MFMA
    gemm_mfma_bt<<<dim3(32, 4), blk, 0, stream>>>(insb + 0ul * 4194304, H, Wrb, H, rb, KDIM, H);
    gemm_mfma_bt<<<dim3(32, 4), blk, 0, stream>>>(insb + 1ul * 4194304, H, Wkb, H, kb, KDIM, H);
    gemm_mfma_bt<<<dim3(32, 8), blk, 0, stream>>>(insb + 2ul * 4194304, H, Wvb, H, vb, VDIM, H);
    gemm_mfma_bt<<<dim3(32, 8), blk, 0, stream>>>(insb + 3ul * 4194304, H, Wgb, H, gb, VDIM, H);

    // sequential RWKV scan -> o[b,l,h,v]
    scan_kernel<<<dim3(256), blk, 0, stream>>>(rb, kb, vb, dec, bonus, o);

    // per-head LN + swish gate -> fp16 gated
    ln_gate_kernel<<<dim3(4096), blk, 0, stream>>>(o, gb, lnw, lnb, gatedb);

    // out = gated @ Wo^T  (fp16 MFMA, f32 out)
    gemm_mfma_bt<<<dim3(32, 8), blk, 0, stream>>>(gatedb, VDIM, Wob, VDIM, out, H, VDIM);
}

// Round 4
// 938.656 us; speedup vs baseline: 1.9148x; 1.0225x over previous
//
#include <hip/hip_runtime.h>
#include <cstdint>
#include <cstddef>

#define H     1024
#define LSEQ  2048
#define NHH   4
#define DKK   128
#define DVV   256
#define KDIM  512
#define VDIM  1024
#define GRR   64
#define MTOT  4096   // B*L

enum { ASRC_PLAIN = 0, ASRC_LERPX = 1 };
enum { EPI_NONE = 0, EPI_TANH = 1, EPI_LERP = 2, EPI_DEC = 3 };

typedef __attribute__((ext_vector_type(8))) _Float16 half8;
typedef __attribute__((ext_vector_type(4))) float f32x4;

static __device__ __forceinline__ unsigned short f2h(float f) {
    _Float16 h = (_Float16)f;          // v_cvt_f16_f32, RNE
    union { _Float16 h; unsigned short u; } c;
    c.h = h;
    return c.u;
}

// DPP-based partial-wave reduction step: return x + dpp_move(x, CTRL). Pure VALU.
template<int CTRL>
static __device__ __forceinline__ float dpp_add(float x) {
    int xi = __float_as_int(x);
    int mv = __builtin_amdgcn_update_dpp(0, xi, CTRL, 0xf, 0xf, true);
    return x + __int_as_float(mv);
}

// ---------------------------------------------------------------------------
// f32 VALU GEMM (small/awkward shapes): C[m][n] = sum_k A[m][k+acol]*B[n][k+bcol]
// ---------------------------------------------------------------------------
template<int ASRC, int EPI>
__global__ __launch_bounds__(256) void gemm_bt(
    const float* __restrict__ A, int lda, int acol,
    const float* __restrict__ B, int ldb, int bcol,
    float* __restrict__ Cf, unsigned short* __restrict__ C2, int ldc,
    int M, int N, int K,
    const float* __restrict__ xsrc,   // LERPX staging / LERP epilogue (ld = H)
    const float* __restrict__ mux,    // LERPX
    const float* __restrict__ bias)   // LERP: x_bias row; DEC: bw2
{
    __shared__ float As[16][64];
    __shared__ float Bs[16][64];
    const int m0 = blockIdx.x * 64;
    const int n0 = blockIdx.y * 64;
    const int t  = threadIdx.x;
    const int tx = t & 15, ty = t >> 4;
    const int sm = t >> 2;          // staging row 0..63
    const int sq = (t & 3) * 4;     // staging k-quad

    float acc[4][4];
#pragma unroll
    for (int i = 0; i < 4; i++)
#pragma unroll
        for (int j = 0; j < 4; j++) acc[i][j] = 0.f;

    for (int k0 = 0; k0 < K; k0 += 16) {
        {   // stage A (M always multiple of 64 -> no guard)
            const int m = m0 + sm;
            float4 av;
            if constexpr (ASRC == ASRC_PLAIN) {
                av = *(const float4*)(A + (size_t)m * lda + acol + k0 + sq);
            } else {
                const float4 xv = *(const float4*)(xsrc + (size_t)m * lda + k0 + sq);
                float4 pv = make_float4(0.f, 0.f, 0.f, 0.f);
                if ((m & (LSEQ - 1)) != 0)
                    pv = *(const float4*)(xsrc + (size_t)(m - 1) * lda + k0 + sq);
                const float4 mv = *(const float4*)(mux + k0 + sq);
                av.x = xv.x + (pv.x - xv.x) * mv.x;
                av.y = xv.y + (pv.y - xv.y) * mv.y;
                av.z = xv.z + (pv.z - xv.z) * mv.z;
                av.w = xv.w + (pv.w - xv.w) * mv.w;
            }
            As[sq + 0][sm] = av.x; As[sq + 1][sm] = av.y;
            As[sq + 2][sm] = av.z; As[sq + 3][sm] = av.w;
        }
        {   // stage B with N guard (N=160 case)
            const int n = n0 + sm;
            float4 bv = make_float4(0.f, 0.f, 0.f, 0.f);
            if (n < N) bv = *(const float4*)(B + (size_t)n * ldb + bcol + k0 + sq);
            Bs[sq + 0][sm] = bv.x; Bs[sq + 1][sm] = bv.y;
            Bs[sq + 2][sm] = bv.z; Bs[sq + 3][sm] = bv.w;
        }
        __syncthreads();
#pragma unroll
        for (int kk = 0; kk < 16; kk++) {
            const float4 a = *(const float4*)&As[kk][ty * 4];
            const float4 b = *(const float4*)&Bs[kk][tx * 4];
            const float av2[4] = {a.x, a.y, a.z, a.w};
            const float bv2[4] = {b.x, b.y, b.z, b.w};
#pragma unroll
            for (int i = 0; i < 4; i++)
#pragma unroll
                for (int j = 0; j < 4; j++) acc[i][j] += av2[i] * bv2[j];
        }
        __syncthreads();
    }

    const int nbase = n0 + tx * 4;
    if (nbase >= N) return;
#pragma unroll
    for (int i = 0; i < 4; i++) {
        const int m = m0 + ty * 4 + i;
        float4 r = make_float4(acc[i][0], acc[i][1], acc[i][2], acc[i][3]);
        if constexpr (EPI == EPI_TANH) {
            r.x = tanhf(r.x); r.y = tanhf(r.y); r.z = tanhf(r.z); r.w = tanhf(r.w);
        } else if constexpr (EPI == EPI_DEC) {
            const float4 bb = *(const float4*)(bias + nbase);
            r.x = expf(-expf(r.x + bb.x));
            r.y = expf(-expf(r.y + bb.y));
            r.z = expf(-expf(r.z + bb.z));
            r.w = expf(-expf(r.w + bb.w));
        } else if constexpr (EPI == EPI_LERP) {
            const float4 bb = *(const float4*)(bias + nbase);
            const float4 xv = *(const float4*)(xsrc + (size_t)m * H + nbase);
            float4 pv = make_float4(0.f, 0.f, 0.f, 0.f);
            if ((m & (LSEQ - 1)) != 0)
                pv = *(const float4*)(xsrc + (size_t)(m - 1) * H + nbase);
            r.x = xv.x + (pv.x - xv.x) * (r.x + bb.x);
            r.y = xv.y + (pv.y - xv.y) * (r.y + bb.y);
            r.z = xv.z + (pv.z - xv.z) * (r.z + bb.z);
            r.w = xv.w + (pv.w - xv.w) * (r.w + bb.w);
        }
        if (Cf) *(float4*)(Cf + (size_t)m * ldc + nbase) = r;
        if (C2) {
            ushort4 p;
            p.x = f2h(r.x); p.y = f2h(r.y); p.z = f2h(r.z); p.w = f2h(r.w);
            *(ushort4*)(C2 + (size_t)m * ldc + nbase) = p;
        }
    }
}

// ---------------------------------------------------------------------------
// fp16 MFMA GEMM (m97 structure): C[m][n] = sum_k A[m][k] * B[n][k], f32 out.
// ---------------------------------------------------------------------------
__global__ __launch_bounds__(256) void gemm_mfma_bt(
    const unsigned short* __restrict__ A, int lda,
    const unsigned short* __restrict__ B, int ldb,
    float* __restrict__ C, int ldc, int K)
{
    __shared__ __align__(16) unsigned short As[128 * 32];
    __shared__ __align__(16) unsigned short Bs[128 * 32];
    const int t    = threadIdx.x;
    const int w    = t >> 6;
    const int lane = t & 63;
    const int m0 = blockIdx.x * 128;
    const int n0 = blockIdx.y * 128;
    const int mw = (w & 1) * 64;
    const int nw = (w >> 1) * 64;
    const int l15 = lane & 15;
    const int q4  = lane >> 4;

    f32x4 acc[4][4];
#pragma unroll
    for (int i = 0; i < 4; i++)
#pragma unroll
        for (int j = 0; j < 4; j++) {
            f32x4 z = {0.f, 0.f, 0.f, 0.f};
            acc[i][j] = z;
        }

    for (int k0 = 0; k0 < K; k0 += 32) {
        __syncthreads();   // previous-iter LDS readers done
#pragma unroll
        for (int jj = 0; jj < 2; jj++) {
            const int c   = w * 128 + jj * 64 + lane;   // 16B chunk id
            const int row = c >> 2;
            const int col = (c & 3) * 8;
            __builtin_amdgcn_global_load_lds(
                (const __attribute__((address_space(1))) void*)(A + (size_t)(m0 + row) * lda + k0 + col),
                (__attribute__((address_space(3))) void*)((char*)As + (w * 128 + jj * 64) * 16),
                16, 0, 0);
            __builtin_amdgcn_global_load_lds(
                (const __attribute__((address_space(1))) void*)(B + (size_t)(n0 + row) * ldb + k0 + col),
                (__attribute__((address_space(3))) void*)((char*)Bs + (w * 128 + jj * 64) * 16),
                16, 0, 0);
        }
        __syncthreads();   // drain global_load_lds

        half8 a[4], b[4];
#pragma unroll
        for (int i = 0; i < 4; i++)
            a[i] = *(const half8*)(As + (mw + i * 16 + l15) * 32 + q4 * 8);
#pragma unroll
        for (int j = 0; j < 4; j++)
            b[j] = *(const half8*)(Bs + (nw + j * 16 + l15) * 32 + q4 * 8);
#pragma unroll
        for (int i = 0; i < 4; i++)
#pragma unroll
            for (int j = 0; j < 4; j++)
                acc[i][j] = __builtin_amdgcn_mfma_f32_16x16x32_f16(a[i], b[j], acc[i][j], 0, 0, 0);
    }

#pragma unroll
    for (int i = 0; i < 4; i++) {
        const int m_base = m0 + mw + i * 16 + q4 * 4;
#pragma unroll
        for (int j = 0; j < 4; j++) {
            const int n = n0 + nw + j * 16 + l15;
#pragma unroll
            for (int r = 0; r < 4; r++)
                C[(size_t)(m_base + r) * ldc + n] = acc[i][j][r];
        }
    }
}

// ---------------------------------------------------------------------------
// Weight f32 -> fp16 pack (Wr|Wk|Wv|Wg|Wo -> one contiguous buffer)
// ---------------------------------------------------------------------------
__global__ __launch_bounds__(256) void cvt_weights(
    const float* __restrict__ Wr, const float* __restrict__ Wk,
    const float* __restrict__ Wv, const float* __restrict__ Wg,
    const float* __restrict__ Wo, unsigned short* __restrict__ out)
{
    const int i4 = (blockIdx.x * 256 + threadIdx.x) * 4;
    const float* src; int off;
    if      (i4 <  524288) { src = Wr; off = i4; }
    else if (i4 < 1048576) { src = Wk; off = i4 -  524288; }
    else if (i4 < 2097152) { src = Wv; off = i4 - 1048576; }
    else if (i4 < 3145728) { src = Wg; off = i4 - 2097152; }
    else                   { src = Wo; off = i4 - 3145728; }
    const float4 v = *(const float4*)(src + off);
    ushort4 o4;
    o4.x = f2h(v.x); o4.y = f2h(v.y); o4.z = f2h(v.z); o4.w = f2h(v.w);
    *(ushort4*)(out + i4) = o4;
}

// ---------------------------------------------------------------------------
// RWKV-6 scan v3: DS-op-free. 256 blocks = (b, h, vchunk of 8).
// 256 threads: kg = t&31 owns k = kg*4..+3, vl = t>>5 owns one v.
// r/k/dec/v read directly from global with a 4-step register pipeline
// (VMEM pipe, L1/L2 serve the duplicates); reduction over the 32 kg-lanes
// via 5 DPP adds (pure VALU, result in lane 31 of each half-wave).
// No LDS, no barriers, no shuffles.
// ---------------------------------------------------------------------------
__global__ __launch_bounds__(256) void scan_kernel(
    const float* __restrict__ r, const float* __restrict__ k,
    const float* __restrict__ v, const float* __restrict__ dec,
    const float* __restrict__ bonus, float* __restrict__ o)
{
    const int vc = blockIdx.x & 31;
    const int bh = blockIdx.x >> 5;
    const int b  = bh >> 2;
    const int h  = bh & 3;
    const int t  = threadIdx.x;
    const int kg = t & 31;
    const int vl = t >> 5;

    float S[4] = {0.f, 0.f, 0.f, 0.f}, u[4];
#pragma unroll
    for (int j = 0; j < 4; j++) u[j] = bonus[h * DKK + kg * 4 + j];

    const float* rp = r   + (size_t)b * LSEQ * KDIM + h * DKK + kg * 4;
    const float* kp = k   + (size_t)b * LSEQ * KDIM + h * DKK + kg * 4;
    const float* dp = dec + (size_t)b * LSEQ * KDIM + h * DKK + kg * 4;
    const float* vp = v   + (size_t)b * LSEQ * VDIM + h * DVV + vc * 8 + vl;
    float*       op = o   + (size_t)b * LSEQ * VDIM + h * DVV + vc * 8 + vl;

    float4 cr[4], ck[4], cd[4];
    float  cv[4];
#pragma unroll
    for (int s = 0; s < 4; s++) {
        cr[s] = *(const float4*)(rp + s * KDIM);
        ck[s] = *(const float4*)(kp + s * KDIM);
        cd[s] = *(const float4*)(dp + s * KDIM);
        cv[s] = vp[s * VDIM];
    }

    for (int t0 = 0; t0 < LSEQ; t0 += 4) {
        float4 nr[4], nk[4], nd[4];
        float  nv[4];
#pragma unroll
        for (int s = 0; s < 4; s++) {
            nr[s] = make_float4(0.f, 0.f, 0.f, 0.f);
            nk[s] = nr[s]; nd[s] = nr[s]; nv[s] = 0.f;
        }
        if (t0 + 4 < LSEQ) {
#pragma unroll
            for (int s = 0; s < 4; s++) {
                const int ts = t0 + 4 + s;
                nr[s] = *(const float4*)(rp + ts * KDIM);
                nk[s] = *(const float4*)(kp + ts * KDIM);
                nd[s] = *(const float4*)(dp + ts * KDIM);
                nv[s] = vp[ts * VDIM];
            }
        }
#pragma unroll
        for (int s = 0; s < 4; s++) {
            const float  vv = cv[s];
            const float4 rr = cr[s];
            const float4 kk = ck[s];
            const float4 dd = cd[s];
            float kv, tmp, part;
            kv = kk.x * vv; tmp = fmaf(u[0], kv, S[0]); part = rr.x * tmp;            S[0] = fmaf(dd.x, S[0], kv);
            kv = kk.y * vv; tmp = fmaf(u[1], kv, S[1]); part = fmaf(rr.y, tmp, part); S[1] = fmaf(dd.y, S[1], kv);
            kv = kk.z * vv; tmp = fmaf(u[2], kv, S[2]); part = fmaf(rr.z, tmp, part); S[2] = fmaf(dd.z, S[2], kv);
            kv = kk.w * vv; tmp = fmaf(u[3], kv, S[3]); part = fmaf(rr.w, tmp, part); S[3] = fmaf(dd.w, S[3], kv);
            // sum over the 32 kg-lanes of this half-wave (result in lane 31/63)
            part = dpp_add<0xB1>(part);    // quad_perm xor1
            part = dpp_add<0x4E>(part);    // quad_perm xor2
            part = dpp_add<0x141>(part);   // row_half_mirror (xor4-equiv)
            part = dpp_add<0x140>(part);   // row_mirror (xor8-equiv)
            part = dpp_add<0x142>(part);   // row_bcast15 (combine 16-rows)
            if (kg == 31) op[(t0 + s) * VDIM] = part;
        }
#pragma unroll
        for (int s = 0; s < 4; s++) {
            cr[s] = nr[s]; ck[s] = nk[s]; cd[s] = nd[s]; cv[s] = nv[s];
        }
    }
}

// ---------------------------------------------------------------------------
// Per-head LayerNorm (biased var) + swish gate -> fp16. One wave per (m,h).
// ---------------------------------------------------------------------------
__global__ __launch_bounds__(256) void ln_gate_kernel(
    const float* __restrict__ o, const float* __restrict__ g,
    const float* __restrict__ lnw, const float* __restrict__ lnb,
    unsigned short* __restrict__ out)
{
    const int m    = blockIdx.x;
    const int t    = threadIdx.x;
    const int h    = t >> 6;
    const int lane = t & 63;
    const size_t base = (size_t)m * VDIM + (size_t)h * DVV + lane * 4;
    const float4 ov = *(const float4*)(o + base);
    float sum = ov.x + ov.y + ov.z + ov.w;
    float sq  = ov.x * ov.x + ov.y * ov.y + ov.z * ov.z + ov.w * ov.w;
#pragma unroll
    for (int off = 1; off < 64; off <<= 1) {
        sum += __shfl_xor(sum, off);
        sq  += __shfl_xor(sq, off);
    }
    const float mean = sum * (1.f / DVV);
    const float var  = sq * (1.f / DVV) - mean * mean;
    const float rstd = rsqrtf(var + 1e-5f);
    const float4 gv = *(const float4*)(g + base);
    const float4 wv = *(const float4*)(lnw + lane * 4);
    const float4 bv = *(const float4*)(lnb + lane * 4);
    float4 res;
    res.x = ((ov.x - mean) * rstd * wv.x + bv.x) * (gv.x / (1.f + expf(-gv.x)));
    res.y = ((ov.y - mean) * rstd * wv.y + bv.y) * (gv.y / (1.f + expf(-gv.y)));
    res.z = ((ov.z - mean) * rstd * wv.z + bv.z) * (gv.z / (1.f + expf(-gv.z)));
    res.w = ((ov.w - mean) * rstd * wv.w + bv.w) * (gv.w / (1.f + expf(-gv.w)));
    ushort4 p;
    p.x = f2h(res.x); p.y = f2h(res.y); p.z = f2h(res.z); p.w = f2h(res.w);
    *(ushort4*)(out + base) = p;
}

extern "C" void kernel_launch(void* const* d_in, const int* in_sizes, int n_in,
                              void* d_out, int out_size, void* d_ws, size_t ws_size,
                              hipStream_t stream)
{
    const float* x     = (const float*)d_in[0];
    const float* mu_x  = (const float*)d_in[1];
    const float* Wx1   = (const float*)d_in[2];
    const float* Wx2   = (const float*)d_in[3];
    const float* xb    = (const float*)d_in[4];
    const float* Wr    = (const float*)d_in[5];
    const float* Wk    = (const float*)d_in[6];
    const float* Wv    = (const float*)d_in[7];
    const float* Wg    = (const float*)d_in[8];
    const float* Ww1   = (const float*)d_in[9];
    const float* Ww2   = (const float*)d_in[10];
    const float* bw2   = (const float*)d_in[11];
    const float* bonus = (const float*)d_in[12];
    const float* lnw   = (const float*)d_in[13];
    const float* lnb   = (const float*)d_in[14];
    const float* Wo    = (const float*)d_in[15];
    float* out = (float*)d_out;
    (void)in_sizes; (void)n_in; (void)out_size; (void)ws_size;

    float* ws = (float*)d_ws;
    // f32 regions
    float* xp    = ws;                          // 655360
    float* in_w  = ws + 655360;                 // 4194304  (w-branch lerp, f32)
    float* insbf = ws + 4849664;                // 8388608 f32-slots = 4 fp16 bufs
    float* rb    = ws + 13238272;               // 2097152
    float* kb    = ws + 15335424;               // 2097152
    float* vb    = ws + 17432576;               // 4194304
    float* gb    = ws + 21626880;               // 4194304
    float* wlow  = ws + 25821184;               // 262144
    float* dec   = ws + 26083328;               // 2097152
    float* wbf   = ws + 28180480;               // 2097152 f32-slots = 4194304 fp16
    // fp16 views
    unsigned short* insb   = (unsigned short*)insbf;      // 4 x 4194304
    unsigned short* Wb     = (unsigned short*)wbf;
    unsigned short* Wrb    = Wb;
    unsigned short* Wkb    = Wb +  524288;
    unsigned short* Wvb    = Wb + 1048576;
    unsigned short* Wgb    = Wb + 2097152;
    unsigned short* Wob    = Wb + 3145728;
    // aliases over consumed regions
    float*          o      = insbf;                       // over insb slots 0,1
    unsigned short* gatedb = insb + 2ul * 4194304;        // over insb slot 2 (v)

    dim3 blk(256);

    cvt_weights<<<dim3(4096), blk, 0, stream>>>(Wr, Wk, Wv, Wg, Wo, Wb);

    // xp = tanh(lerp(x, mu_x) @ Wx1^T)
    gemm_bt<ASRC_LERPX, EPI_TANH><<<dim3(64, 3), blk, 0, stream>>>(
        x, H, 0, Wx1, H, 0, xp, nullptr, 160, MTOT, 160, H, x, mu_x, nullptr);

    // in_n = x + delta * (xp_n @ Wx2_n^T + x_bias_n)  -> fp16 (w-branch: f32)
    for (int n = 0; n < 5; n++) {
        float*          Cf = (n == 1) ? in_w : nullptr;
        unsigned short* C2 = (n == 1) ? nullptr : insb + (size_t)(n == 0 ? 0 : n - 1) * 4194304;
        gemm_bt<ASRC_PLAIN, EPI_LERP><<<dim3(64, 16), blk, 0, stream>>>(
            xp, 160, n * 32, Wx2, 160, n * 32, Cf, C2, H,
            MTOT, H, 32, x, nullptr, xb + n * H);
    }

    // w LoRA (f32): wlow = tanh(in_w @ Ww1^T);  dec = exp(-exp(wlow @ Ww2^T + bw2))
    gemm_bt<ASRC_PLAIN, EPI_TANH><<<dim3(64, 1), blk, 0, stream>>>(
        in_w, H, 0, Ww1, H, 0, wlow, nullptr, GRR, MTOT, GRR, H, nullptr, nullptr, nullptr);
    gemm_bt<ASRC_PLAIN, EPI_DEC><<<dim3(64, 8), blk, 0, stream>>>(
        wlow, GRR, 0, Ww2, GRR, 0, dec, nullptr, KDIM, MTOT, KDIM, GRR, nullptr, nullptr, bw2);

    // big projections: fp16 MFMA
    gemm_mfma_bt<<<dim3(32, 4), blk, 0, stream>>>(insb + 0ul * 4194304, H, Wrb, H, rb, KDIM, H);
    gemm_mfma_bt<<<dim3(32, 4), blk, 0, stream>>>(insb + 1ul * 4194304, H, Wkb, H, kb, KDIM, H);
    gemm_mfma_bt<<<dim3(32, 8), blk, 0, stream>>>(insb + 2ul * 4194304, H, Wvb, H, vb, VDIM, H);
    gemm_mfma_bt<<<dim3(32, 8), blk, 0, stream>>>(insb + 3ul * 4194304, H, Wgb, H, gb, VDIM, H);

    // sequential RWKV scan -> o[b,l,h,v]
    scan_kernel<<<dim3(256), blk, 0, stream>>>(rb, kb, vb, dec, bonus, o);

    // per-head LN + swish gate -> fp16 gated
    ln_gate_kernel<<<dim3(4096), blk, 0, stream>>>(o, gb, lnw, lnb, gatedb);

    // out = gated @ Wo^T  (fp16 MFMA, f32 out)
    gemm_mfma_bt<<<dim3(32, 8), blk, 0, stream>>>(gatedb, VDIM, Wob, VDIM, out, H, VDIM);
}

// Round 5
// 725.037 us; speedup vs baseline: 2.4790x; 1.2946x over previous
//
#include <hip/hip_runtime.h>
#include <cstdint>
#include <cstddef>

#define H     1024
#define LSEQ  2048
#define NHH   4
#define DKK   128
#define DVV   256
#define KDIM  512
#define VDIM  1024
#define GRR   64
#define MTOT  4096   // B*L
#define SEGL  256    // scan segment length
#define NSEG  8

enum { ASRC_PLAIN = 0, ASRC_LERPX = 1 };
enum { EPI_NONE = 0, EPI_TANH = 1, EPI_LERP = 2, EPI_DEC = 3 };

typedef __attribute__((ext_vector_type(8))) _Float16 half8;
typedef __attribute__((ext_vector_type(4))) float f32x4;

static __device__ __forceinline__ unsigned short f2h(float f) {
    _Float16 h = (_Float16)f;          // v_cvt_f16_f32, RNE
    union { _Float16 h; unsigned short u; } c;
    c.h = h;
    return c.u;
}

// DPP-based partial-wave reduction step: return x + dpp_move(x, CTRL). Pure VALU.
template<int CTRL>
static __device__ __forceinline__ float dpp_add(float x) {
    int xi = __float_as_int(x);
    int mv = __builtin_amdgcn_update_dpp(0, xi, CTRL, 0xf, 0xf, true);
    return x + __int_as_float(mv);
}

// ---------------------------------------------------------------------------
// f32 VALU GEMM (small/awkward shapes): C[m][n] = sum_k A[m][k+acol]*B[n][k+bcol]
// ---------------------------------------------------------------------------
template<int ASRC, int EPI>
__global__ __launch_bounds__(256) void gemm_bt(
    const float* __restrict__ A, int lda, int acol,
    const float* __restrict__ B, int ldb, int bcol,
    float* __restrict__ Cf, unsigned short* __restrict__ C2, int ldc,
    int M, int N, int K,
    const float* __restrict__ xsrc,   // LERPX staging / LERP epilogue (ld = H)
    const float* __restrict__ mux,    // LERPX
    const float* __restrict__ bias)   // LERP: x_bias row; DEC: bw2
{
    __shared__ float As[16][64];
    __shared__ float Bs[16][64];
    const int m0 = blockIdx.x * 64;
    const int n0 = blockIdx.y * 64;
    const int t  = threadIdx.x;
    const int tx = t & 15, ty = t >> 4;
    const int sm = t >> 2;          // staging row 0..63
    const int sq = (t & 3) * 4;     // staging k-quad

    float acc[4][4];
#pragma unroll
    for (int i = 0; i < 4; i++)
#pragma unroll
        for (int j = 0; j < 4; j++) acc[i][j] = 0.f;

    for (int k0 = 0; k0 < K; k0 += 16) {
        {   // stage A (M always multiple of 64 -> no guard)
            const int m = m0 + sm;
            float4 av;
            if constexpr (ASRC == ASRC_PLAIN) {
                av = *(const float4*)(A + (size_t)m * lda + acol + k0 + sq);
            } else {
                const float4 xv = *(const float4*)(xsrc + (size_t)m * lda + k0 + sq);
                float4 pv = make_float4(0.f, 0.f, 0.f, 0.f);
                if ((m & (LSEQ - 1)) != 0)
                    pv = *(const float4*)(xsrc + (size_t)(m - 1) * lda + k0 + sq);
                const float4 mv = *(const float4*)(mux + k0 + sq);
                av.x = xv.x + (pv.x - xv.x) * mv.x;
                av.y = xv.y + (pv.y - xv.y) * mv.y;
                av.z = xv.z + (pv.z - xv.z) * mv.z;
                av.w = xv.w + (pv.w - xv.w) * mv.w;
            }
            As[sq + 0][sm] = av.x; As[sq + 1][sm] = av.y;
            As[sq + 2][sm] = av.z; As[sq + 3][sm] = av.w;
        }
        {   // stage B with N guard (N=160 case)
            const int n = n0 + sm;
            float4 bv = make_float4(0.f, 0.f, 0.f, 0.f);
            if (n < N) bv = *(const float4*)(B + (size_t)n * ldb + bcol + k0 + sq);
            Bs[sq + 0][sm] = bv.x; Bs[sq + 1][sm] = bv.y;
            Bs[sq + 2][sm] = bv.z; Bs[sq + 3][sm] = bv.w;
        }
        __syncthreads();
#pragma unroll
        for (int kk = 0; kk < 16; kk++) {
            const float4 a = *(const float4*)&As[kk][ty * 4];
            const float4 b = *(const float4*)&Bs[kk][tx * 4];
            const float av2[4] = {a.x, a.y, a.z, a.w};
            const float bv2[4] = {b.x, b.y, b.z, b.w};
#pragma unroll
            for (int i = 0; i < 4; i++)
#pragma unroll
                for (int j = 0; j < 4; j++) acc[i][j] += av2[i] * bv2[j];
        }
        __syncthreads();
    }

    const int nbase = n0 + tx * 4;
    if (nbase >= N) return;
#pragma unroll
    for (int i = 0; i < 4; i++) {
        const int m = m0 + ty * 4 + i;
        float4 r = make_float4(acc[i][0], acc[i][1], acc[i][2], acc[i][3]);
        if constexpr (EPI == EPI_TANH) {
            r.x = tanhf(r.x); r.y = tanhf(r.y); r.z = tanhf(r.z); r.w = tanhf(r.w);
        } else if constexpr (EPI == EPI_DEC) {
            const float4 bb = *(const float4*)(bias + nbase);
            r.x = expf(-expf(r.x + bb.x));
            r.y = expf(-expf(r.y + bb.y));
            r.z = expf(-expf(r.z + bb.z));
            r.w = expf(-expf(r.w + bb.w));
        } else if constexpr (EPI == EPI_LERP) {
            const float4 bb = *(const float4*)(bias + nbase);
            const float4 xv = *(const float4*)(xsrc + (size_t)m * H + nbase);
            float4 pv = make_float4(0.f, 0.f, 0.f, 0.f);
            if ((m & (LSEQ - 1)) != 0)
                pv = *(const float4*)(xsrc + (size_t)(m - 1) * H + nbase);
            r.x = xv.x + (pv.x - xv.x) * (r.x + bb.x);
            r.y = xv.y + (pv.y - xv.y) * (r.y + bb.y);
            r.z = xv.z + (pv.z - xv.z) * (r.z + bb.z);
            r.w = xv.w + (pv.w - xv.w) * (r.w + bb.w);
        }
        if (Cf) *(float4*)(Cf + (size_t)m * ldc + nbase) = r;
        if (C2) {
            ushort4 p;
            p.x = f2h(r.x); p.y = f2h(r.y); p.z = f2h(r.z); p.w = f2h(r.w);
            *(ushort4*)(C2 + (size_t)m * ldc + nbase) = p;
        }
    }
}

// ---------------------------------------------------------------------------
// fp16 MFMA GEMM (m97 structure): C[m][n] = sum_k A[m][k] * B[n][k], f32 out.
// ---------------------------------------------------------------------------
__global__ __launch_bounds__(256) void gemm_mfma_bt(
    const unsigned short* __restrict__ A, int lda,
    const unsigned short* __restrict__ B, int ldb,
    float* __restrict__ C, int ldc, int K)
{
    __shared__ __align__(16) unsigned short As[128 * 32];
    __shared__ __align__(16) unsigned short Bs[128 * 32];
    const int t    = threadIdx.x;
    const int w    = t >> 6;
    const int lane = t & 63;
    const int m0 = blockIdx.x * 128;
    const int n0 = blockIdx.y * 128;
    const int mw = (w & 1) * 64;
    const int nw = (w >> 1) * 64;
    const int l15 = lane & 15;
    const int q4  = lane >> 4;

    f32x4 acc[4][4];
#pragma unroll
    for (int i = 0; i < 4; i++)
#pragma unroll
        for (int j = 0; j < 4; j++) {
            f32x4 z = {0.f, 0.f, 0.f, 0.f};
            acc[i][j] = z;
        }

    for (int k0 = 0; k0 < K; k0 += 32) {
        __syncthreads();   // previous-iter LDS readers done
#pragma unroll
        for (int jj = 0; jj < 2; jj++) {
            const int c   = w * 128 + jj * 64 + lane;   // 16B chunk id
            const int row = c >> 2;
            const int col = (c & 3) * 8;
            __builtin_amdgcn_global_load_lds(
                (const __attribute__((address_space(1))) void*)(A + (size_t)(m0 + row) * lda + k0 + col),
                (__attribute__((address_space(3))) void*)((char*)As + (w * 128 + jj * 64) * 16),
                16, 0, 0);
            __builtin_amdgcn_global_load_lds(
                (const __attribute__((address_space(1))) void*)(B + (size_t)(n0 + row) * ldb + k0 + col),
                (__attribute__((address_space(3))) void*)((char*)Bs + (w * 128 + jj * 64) * 16),
                16, 0, 0);
        }
        __syncthreads();   // drain global_load_lds

        half8 a[4], b[4];
#pragma unroll
        for (int i = 0; i < 4; i++)
            a[i] = *(const half8*)(As + (mw + i * 16 + l15) * 32 + q4 * 8);
#pragma unroll
        for (int j = 0; j < 4; j++)
            b[j] = *(const half8*)(Bs + (nw + j * 16 + l15) * 32 + q4 * 8);
#pragma unroll
        for (int i = 0; i < 4; i++)
#pragma unroll
            for (int j = 0; j < 4; j++)
                acc[i][j] = __builtin_amdgcn_mfma_f32_16x16x32_f16(a[i], b[j], acc[i][j], 0, 0, 0);
    }

#pragma unroll
    for (int i = 0; i < 4; i++) {
        const int m_base = m0 + mw + i * 16 + q4 * 4;
#pragma unroll
        for (int j = 0; j < 4; j++) {
            const int n = n0 + nw + j * 16 + l15;
#pragma unroll
            for (int r = 0; r < 4; r++)
                C[(size_t)(m_base + r) * ldc + n] = acc[i][j][r];
        }
    }
}

// ---------------------------------------------------------------------------
// Batched fp16 MFMA GEMM with C-accumulate, for the scan correction:
// o[seg,bh][m,n] += sum_k rt16[m,k] * SentryT16[n,k].  M=N=256, K=128.
// grid (2, 2, 56): z = (seg-1)*8 + bh.
// ---------------------------------------------------------------------------
__global__ __launch_bounds__(256) void gemm_mfma_corr(
    const unsigned short* __restrict__ rt16,
    const unsigned short* __restrict__ SentryT16,
    float* __restrict__ o)
{
    const int z   = blockIdx.z;
    const int seg = (z >> 3) + 1;
    const int bh  = z & 7;
    const int b   = bh >> 2, h = bh & 3;
    const unsigned short* A = rt16 + ((size_t)b * LSEQ + seg * SEGL) * KDIM + h * DKK;  // lda=KDIM
    const unsigned short* B = SentryT16 + (size_t)(seg * 8 + bh) * 32768;               // ldb=128
    float* C = o + ((size_t)b * LSEQ + seg * SEGL) * VDIM + h * DVV;                    // ldc=VDIM

    __shared__ __align__(16) unsigned short As[128 * 32];
    __shared__ __align__(16) unsigned short Bs[128 * 32];
    const int t    = threadIdx.x;
    const int w    = t >> 6;
    const int lane = t & 63;
    const int m0 = blockIdx.x * 128;
    const int n0 = blockIdx.y * 128;
    const int mw = (w & 1) * 64;
    const int nw = (w >> 1) * 64;
    const int l15 = lane & 15;
    const int q4  = lane >> 4;

    f32x4 acc[4][4];
#pragma unroll
    for (int i = 0; i < 4; i++)
#pragma unroll
        for (int j = 0; j < 4; j++) {
            f32x4 zz = {0.f, 0.f, 0.f, 0.f};
            acc[i][j] = zz;
        }

    for (int k0 = 0; k0 < 128; k0 += 32) {
        __syncthreads();
#pragma unroll
        for (int jj = 0; jj < 2; jj++) {
            const int c   = w * 128 + jj * 64 + lane;
            const int row = c >> 2;
            const int col = (c & 3) * 8;
            __builtin_amdgcn_global_load_lds(
                (const __attribute__((address_space(1))) void*)(A + (size_t)(m0 + row) * KDIM + k0 + col),
                (__attribute__((address_space(3))) void*)((char*)As + (w * 128 + jj * 64) * 16),
                16, 0, 0);
            __builtin_amdgcn_global_load_lds(
                (const __attribute__((address_space(1))) void*)(B + (size_t)(n0 + row) * 128 + k0 + col),
                (__attribute__((address_space(3))) void*)((char*)Bs + (w * 128 + jj * 64) * 16),
                16, 0, 0);
        }
        __syncthreads();

        half8 a[4], bb[4];
#pragma unroll
        for (int i = 0; i < 4; i++)
            a[i] = *(const half8*)(As + (mw + i * 16 + l15) * 32 + q4 * 8);
#pragma unroll
        for (int j = 0; j < 4; j++)
            bb[j] = *(const half8*)(Bs + (nw + j * 16 + l15) * 32 + q4 * 8);
#pragma unroll
        for (int i = 0; i < 4; i++)
#pragma unroll
            for (int j = 0; j < 4; j++)
                acc[i][j] = __builtin_amdgcn_mfma_f32_16x16x32_f16(a[i], bb[j], acc[i][j], 0, 0, 0);
    }

#pragma unroll
    for (int i = 0; i < 4; i++) {
        const int m_base = m0 + mw + i * 16 + q4 * 4;
#pragma unroll
        for (int j = 0; j < 4; j++) {
            const int n = n0 + nw + j * 16 + l15;
#pragma unroll
            for (int rr = 0; rr < 4; rr++)
                C[(size_t)(m_base + rr) * VDIM + n] += acc[i][j][rr];
        }
    }
}

// ---------------------------------------------------------------------------
// Weight f32 -> fp16 pack (Wr|Wk|Wv|Wg|Wo -> one contiguous buffer)
// ---------------------------------------------------------------------------
__global__ __launch_bounds__(256) void cvt_weights(
    const float* __restrict__ Wr, const float* __restrict__ Wk,
    const float* __restrict__ Wv, const float* __restrict__ Wg,
    const float* __restrict__ Wo, unsigned short* __restrict__ out)
{
    const int i4 = (blockIdx.x * 256 + threadIdx.x) * 4;
    const float* src; int off;
    if      (i4 <  524288) { src = Wr; off = i4; }
    else if (i4 < 1048576) { src = Wk; off = i4 -  524288; }
    else if (i4 < 2097152) { src = Wv; off = i4 - 1048576; }
    else if (i4 < 3145728) { src = Wg; off = i4 - 2097152; }
    else                   { src = Wo; off = i4 - 3145728; }
    const float4 v = *(const float4*)(src + off);
    ushort4 o4;
    o4.x = f2h(v.x); o4.y = f2h(v.y); o4.z = f2h(v.z); o4.w = f2h(v.w);
    *(ushort4*)(out + i4) = o4;
}

// ---------------------------------------------------------------------------
// Scan pass 1: segmented RWKV recurrence from S=0.
// 2048 blocks = (seg, bh, vchunk of 8)  -> 8 waves/SIMD, full occupancy.
// Per step also: track running decay product D, write r~ = r*D (fp16, one
// wave per bh), emit segment-final S_loc and total decay D_tot.
// ---------------------------------------------------------------------------
__global__ __launch_bounds__(256) void scan_pass1(
    const float* __restrict__ r, const float* __restrict__ k,
    const float* __restrict__ v, const float* __restrict__ dec,
    const float* __restrict__ bonus, float* __restrict__ o,
    unsigned short* __restrict__ rt16, float* __restrict__ Sloc,
    float* __restrict__ Dtot)
{
    const int vc  = blockIdx.x & 31;
    const int bh  = (blockIdx.x >> 5) & 7;
    const int seg = blockIdx.x >> 8;
    const int b   = bh >> 2;
    const int h   = bh & 3;
    const int t   = threadIdx.x;
    const int kg  = t & 31;
    const int vl  = t >> 5;
    const bool wlead = (vc == 0) && (vl == 0);   // lanes 0..31 of wave 0, vc==0 block

    float S[4] = {0.f, 0.f, 0.f, 0.f}, D[4] = {1.f, 1.f, 1.f, 1.f}, u[4];
#pragma unroll
    for (int j = 0; j < 4; j++) u[j] = bonus[h * DKK + kg * 4 + j];

    const size_t row0 = (size_t)b * LSEQ + (size_t)seg * SEGL;
    const float* rp = r   + row0 * KDIM + h * DKK + kg * 4;
    const float* kp = k   + row0 * KDIM + h * DKK + kg * 4;
    const float* dp = dec + row0 * KDIM + h * DKK + kg * 4;
    const float* vp = v   + row0 * VDIM + h * DVV + vc * 8 + vl;
    float*       op = o   + row0 * VDIM + h * DVV + vc * 8 + vl;
    unsigned short* rt = rt16 + row0 * KDIM + h * DKK + kg * 4;

    float4 cr[4], ck[4], cd[4];
    float  cv[4];
#pragma unroll
    for (int s = 0; s < 4; s++) {
        cr[s] = *(const float4*)(rp + s * KDIM);
        ck[s] = *(const float4*)(kp + s * KDIM);
        cd[s] = *(const float4*)(dp + s * KDIM);
        cv[s] = vp[s * VDIM];
    }

    for (int t0 = 0; t0 < SEGL; t0 += 4) {
        float4 nr[4], nk[4], nd[4];
        float  nv[4];
#pragma unroll
        for (int s = 0; s < 4; s++) {
            nr[s] = make_float4(0.f, 0.f, 0.f, 0.f);
            nk[s] = nr[s]; nd[s] = nr[s]; nv[s] = 0.f;
        }
        if (t0 + 4 < SEGL) {
#pragma unroll
            for (int s = 0; s < 4; s++) {
                const int ts = t0 + 4 + s;
                nr[s] = *(const float4*)(rp + ts * KDIM);
                nk[s] = *(const float4*)(kp + ts * KDIM);
                nd[s] = *(const float4*)(dp + ts * KDIM);
                nv[s] = vp[ts * VDIM];
            }
        }
#pragma unroll
        for (int s = 0; s < 4; s++) {
            const float  vv = cv[s];
            const float4 rr = cr[s];
            const float4 kk = ck[s];
            const float4 dd = cd[s];
            if (wlead) {   // r~ = r * D (pre-step D = exclusive cumprod), fp16
                ushort4 p;
                p.x = f2h(rr.x * D[0]); p.y = f2h(rr.y * D[1]);
                p.z = f2h(rr.z * D[2]); p.w = f2h(rr.w * D[3]);
                *(ushort4*)(rt + (size_t)(t0 + s) * KDIM) = p;
            }
            float kv, tmp, part;
            kv = kk.x * vv; tmp = fmaf(u[0], kv, S[0]); part = rr.x * tmp;            S[0] = fmaf(dd.x, S[0], kv);
            kv = kk.y * vv; tmp = fmaf(u[1], kv, S[1]); part = fmaf(rr.y, tmp, part); S[1] = fmaf(dd.y, S[1], kv);
            kv = kk.z * vv; tmp = fmaf(u[2], kv, S[2]); part = fmaf(rr.z, tmp, part); S[2] = fmaf(dd.z, S[2], kv);
            kv = kk.w * vv; tmp = fmaf(u[3], kv, S[3]); part = fmaf(rr.w, tmp, part); S[3] = fmaf(dd.w, S[3], kv);
            D[0] *= dd.x; D[1] *= dd.y; D[2] *= dd.z; D[3] *= dd.w;
            // sum over the 32 kg-lanes of this half-wave (result in lane 31/63)
            part = dpp_add<0xB1>(part);    // quad_perm xor1
            part = dpp_add<0x4E>(part);    // quad_perm xor2
            part = dpp_add<0x141>(part);   // row_half_mirror (xor4-equiv)
            part = dpp_add<0x140>(part);   // row_mirror (xor8-equiv)
            part = dpp_add<0x142>(part);   // row_bcast15 (combine 16-rows)
            if (kg == 31) op[(t0 + s) * VDIM] = part;
        }
#pragma unroll
        for (int s = 0; s < 4; s++) {
            cr[s] = nr[s]; ck[s] = nk[s]; cd[s] = nd[s]; cv[s] = nv[s];
        }
    }

    // segment-final state + total decay
    {
        float* sl = Sloc + (size_t)(seg * 8 + bh) * 32768 + (size_t)(kg * 4) * 256 + vc * 8 + vl;
#pragma unroll
        for (int j = 0; j < 4; j++) sl[j * 256] = S[j];
        if (wlead) {
            float* dt = Dtot + (seg * 8 + bh) * 128 + kg * 4;
#pragma unroll
            for (int j = 0; j < 4; j++) dt[j] = D[j];
        }
    }
}

// ---------------------------------------------------------------------------
// Scan pass 2: propagate entry states across segments (8 sequential steps).
// 256 blocks = (bh, vchunk); thread owns same (kg,vl) slice as pass 1.
// Writes Sentry^T (v-major, k-contiguous) as fp16 for the correction GEMM.
// ---------------------------------------------------------------------------
__global__ __launch_bounds__(256) void scan_pass2(
    const float* __restrict__ Sloc, const float* __restrict__ Dtot,
    unsigned short* __restrict__ SentryT16)
{
    const int vc = blockIdx.x & 31;
    const int bh = blockIdx.x >> 5;
    const int t  = threadIdx.x;
    const int kg = t & 31;
    const int vl = t >> 5;

    float S[4] = {0.f, 0.f, 0.f, 0.f};
    for (int p = 0; p < NSEG; p++) {
        unsigned short* st = SentryT16 + (size_t)(p * 8 + bh) * 32768
                             + (size_t)(vc * 8 + vl) * 128 + kg * 4;
        ushort4 pk;
        pk.x = f2h(S[0]); pk.y = f2h(S[1]); pk.z = f2h(S[2]); pk.w = f2h(S[3]);
        *(ushort4*)st = pk;
        if (p < NSEG - 1) {
            const float* sl = Sloc + (size_t)(p * 8 + bh) * 32768
                              + (size_t)(kg * 4) * 256 + vc * 8 + vl;
            const float* dt = Dtot + (p * 8 + bh) * 128 + kg * 4;
#pragma unroll
            for (int j = 0; j < 4; j++) S[j] = dt[j] * S[j] + sl[j * 256];
        }
    }
}

// ---------------------------------------------------------------------------
// Per-head LayerNorm (biased var) + swish gate -> fp16. One wave per (m,h).
// ---------------------------------------------------------------------------
__global__ __launch_bounds__(256) void ln_gate_kernel(
    const float* __restrict__ o, const float* __restrict__ g,
    const float* __restrict__ lnw, const float* __restrict__ lnb,
    unsigned short* __restrict__ out)
{
    const int m    = blockIdx.x;
    const int t    = threadIdx.x;
    const int h    = t >> 6;
    const int lane = t & 63;
    const size_t base = (size_t)m * VDIM + (size_t)h * DVV + lane * 4;
    const float4 ov = *(const float4*)(o + base);
    float sum = ov.x + ov.y + ov.z + ov.w;
    float sq  = ov.x * ov.x + ov.y * ov.y + ov.z * ov.z + ov.w * ov.w;
#pragma unroll
    for (int off = 1; off < 64; off <<= 1) {
        sum += __shfl_xor(sum, off);
        sq  += __shfl_xor(sq, off);
    }
    const float mean = sum * (1.f / DVV);
    const float var  = sq * (1.f / DVV) - mean * mean;
    const float rstd = rsqrtf(var + 1e-5f);
    const float4 gv = *(const float4*)(g + base);
    const float4 wv = *(const float4*)(lnw + lane * 4);
    const float4 bv = *(const float4*)(lnb + lane * 4);
    float4 res;
    res.x = ((ov.x - mean) * rstd * wv.x + bv.x) * (gv.x / (1.f + expf(-gv.x)));
    res.y = ((ov.y - mean) * rstd * wv.y + bv.y) * (gv.y / (1.f + expf(-gv.y)));
    res.z = ((ov.z - mean) * rstd * wv.z + bv.z) * (gv.z / (1.f + expf(-gv.z)));
    res.w = ((ov.w - mean) * rstd * wv.w + bv.w) * (gv.w / (1.f + expf(-gv.w)));
    ushort4 p;
    p.x = f2h(res.x); p.y = f2h(res.y); p.z = f2h(res.z); p.w = f2h(res.w);
    *(ushort4*)(out + base) = p;
}

extern "C" void kernel_launch(void* const* d_in, const int* in_sizes, int n_in,
                              void* d_out, int out_size, void* d_ws, size_t ws_size,
                              hipStream_t stream)
{
    const float* x     = (const float*)d_in[0];
    const float* mu_x  = (const float*)d_in[1];
    const float* Wx1   = (const float*)d_in[2];
    const float* Wx2   = (const float*)d_in[3];
    const float* xb    = (const float*)d_in[4];
    const float* Wr    = (const float*)d_in[5];
    const float* Wk    = (const float*)d_in[6];
    const float* Wv    = (const float*)d_in[7];
    const float* Wg    = (const float*)d_in[8];
    const float* Ww1   = (const float*)d_in[9];
    const float* Ww2   = (const float*)d_in[10];
    const float* bw2   = (const float*)d_in[11];
    const float* bonus = (const float*)d_in[12];
    const float* lnw   = (const float*)d_in[13];
    const float* lnb   = (const float*)d_in[14];
    const float* Wo    = (const float*)d_in[15];
    float* out = (float*)d_out;
    (void)in_sizes; (void)n_in; (void)out_size; (void)ws_size;

    float* ws = (float*)d_ws;
    // f32 regions
    float* xp    = ws;                          // 655360
    float* in_w  = ws + 655360;                 // 4194304  (w-branch lerp, f32; dead after LoRA)
    float* insbf = ws + 4849664;                // 8388608 f32-slots = 4 fp16 bufs
    float* rb    = ws + 13238272;               // 2097152
    float* kb    = ws + 15335424;               // 2097152
    float* vb    = ws + 17432576;               // 4194304
    float* gb    = ws + 21626880;               // 4194304
    float* wlow  = ws + 25821184;               // 262144
    float* dec   = ws + 26083328;               // 2097152
    float* wbf   = ws + 28180480;               // 2097152 f32-slots = 4194304 fp16
    // scan scratch: alias in_w region (dead after the LoRA GEMMs)
    float* Sloc  = in_w;                        // 2097152 words
    float* Dtot  = in_w + 2097152;              // 8192 words
    unsigned short* SentryT16 = (unsigned short*)(in_w + 2105344);  // 2097152 halves
    // fp16 views
    unsigned short* insb   = (unsigned short*)insbf;      // 4 x 4194304 halves
    unsigned short* Wb     = (unsigned short*)wbf;
    unsigned short* Wrb    = Wb;
    unsigned short* Wkb    = Wb +  524288;
    unsigned short* Wvb    = Wb + 1048576;
    unsigned short* Wgb    = Wb + 2097152;
    unsigned short* Wob    = Wb + 3145728;
    // aliases over consumed regions
    float*          o      = insbf;                       // over insb slots 0,1 (consumed)
    unsigned short* gatedb = insb + 2ul * 4194304;        // over insb slot 2 (consumed)
    unsigned short* rt16   = insb + 3ul * 4194304;        // over insb slot 3 (consumed)

    dim3 blk(256);

    cvt_weights<<<dim3(4096), blk, 0, stream>>>(Wr, Wk, Wv, Wg, Wo, Wb);

    // xp = tanh(lerp(x, mu_x) @ Wx1^T)
    gemm_bt<ASRC_LERPX, EPI_TANH><<<dim3(64, 3), blk, 0, stream>>>(
        x, H, 0, Wx1, H, 0, xp, nullptr, 160, MTOT, 160, H, x, mu_x, nullptr);

    // in_n = x + delta * (xp_n @ Wx2_n^T + x_bias_n)  -> fp16 (w-branch: f32)
    for (int n = 0; n < 5; n++) {
        float*          Cf = (n == 1) ? in_w : nullptr;
        unsigned short* C2 = (n == 1) ? nullptr : insb + (size_t)(n == 0 ? 0 : n - 1) * 4194304;
        gemm_bt<ASRC_PLAIN, EPI_LERP><<<dim3(64, 16), blk, 0, stream>>>(
            xp, 160, n * 32, Wx2, 160, n * 32, Cf, C2, H,
            MTOT, H, 32, x, nullptr, xb + n * H);
    }

    // w LoRA (f32): wlow = tanh(in_w @ Ww1^T);  dec = exp(-exp(wlow @ Ww2^T + bw2))
    gemm_bt<ASRC_PLAIN, EPI_TANH><<<dim3(64, 1), blk, 0, stream>>>(
        in_w, H, 0, Ww1, H, 0, wlow, nullptr, GRR, MTOT, GRR, H, nullptr, nullptr, nullptr);
    gemm_bt<ASRC_PLAIN, EPI_DEC><<<dim3(64, 8), blk, 0, stream>>>(
        wlow, GRR, 0, Ww2, GRR, 0, dec, nullptr, KDIM, MTOT, KDIM, GRR, nullptr, nullptr, bw2);

    // big projections: fp16 MFMA
    gemm_mfma_bt<<<dim3(32, 4), blk, 0, stream>>>(insb + 0ul * 4194304, H, Wrb, H, rb, KDIM, H);
    gemm_mfma_bt<<<dim3(32, 4), blk, 0, stream>>>(insb + 1ul * 4194304, H, Wkb, H, kb, KDIM, H);
    gemm_mfma_bt<<<dim3(32, 8), blk, 0, stream>>>(insb + 2ul * 4194304, H, Wvb, H, vb, VDIM, H);
    gemm_mfma_bt<<<dim3(32, 8), blk, 0, stream>>>(insb + 3ul * 4194304, H, Wgb, H, gb, VDIM, H);

    // segmented RWKV scan
    scan_pass1<<<dim3(2048), blk, 0, stream>>>(rb, kb, vb, dec, bonus, o, rt16, Sloc, Dtot);
    scan_pass2<<<dim3(256), blk, 0, stream>>>(Sloc, Dtot, SentryT16);
    gemm_mfma_corr<<<dim3(2, 2, 56), blk, 0, stream>>>(rt16, SentryT16, o);

    // per-head LN + swish gate -> fp16 gated
    ln_gate_kernel<<<dim3(4096), blk, 0, stream>>>(o, gb, lnw, lnb, gatedb);

    // out = gated @ Wo^T  (fp16 MFMA, f32 out)
    gemm_mfma_bt<<<dim3(32, 8), blk, 0, stream>>>(gatedb, VDIM, Wob, VDIM, out, H, VDIM);
}

// Round 6
// 556.023 us; speedup vs baseline: 3.2325x; 1.3040x over previous
//
#include <hip/hip_runtime.h>
#include <cstdint>
#include <cstddef>

#define H     1024
#define LSEQ  2048
#define NHH   4
#define DKK   128
#define DVV   256
#define KDIM  512
#define VDIM  1024
#define GRR   64
#define MTOT  4096   // B*L
#define SEGL  256    // scan segment length
#define NSEG  8

enum { ASRC_PLAIN = 0, ASRC_LERPX = 1 };
enum { EPI_NONE = 0, EPI_TANH = 1, EPI_LERP = 2, EPI_DEC = 3 };

typedef __attribute__((ext_vector_type(8))) _Float16 half8;
typedef __attribute__((ext_vector_type(4))) float f32x4;

static __device__ __forceinline__ unsigned short f2h(float f) {
    _Float16 h = (_Float16)f;          // v_cvt_f16_f32, RNE
    union { _Float16 h; unsigned short u; } c;
    c.h = h;
    return c.u;
}

// DPP-based partial-wave reduction step: return x + dpp_move(x, CTRL). Pure VALU.
template<int CTRL>
static __device__ __forceinline__ float dpp_add(float x) {
    int xi = __float_as_int(x);
    int mv = __builtin_amdgcn_update_dpp(0, xi, CTRL, 0xf, 0xf, true);
    return x + __int_as_float(mv);
}

// ---------------------------------------------------------------------------
// f32 VALU GEMM: C[m][n] = sum_k A[m][k+acol]*B[n][k+bcol]
// EPI_LERP instantiation is the fused 5-way thin-K kernel: blockIdx.z picks
// the mixing branch (acol/bcol += z*32, bias += z*H, C2 += z*slot).
// ---------------------------------------------------------------------------
template<int EPI>
__global__ __launch_bounds__(256) void gemm_bt(
    const float* __restrict__ A, int lda, int acol,
    const float* __restrict__ B, int ldb, int bcol,
    float* __restrict__ Cf, unsigned short* __restrict__ C2, int ldc,
    int M, int N, int K,
    const float* __restrict__ xsrc,   // LERP epilogue source (ld = H)
    const float* __restrict__ bias)   // LERP: x_bias row; DEC: bw2
{
    if constexpr (EPI == EPI_LERP) {
        const int zz = blockIdx.z;
        acol += zz * 32;
        bcol += zz * 32;
        bias += zz * H;
        C2   += (size_t)zz * 4194304;   // fp16 slot stride
    }
    __shared__ float As[16][64];
    __shared__ float Bs[16][64];
    const int m0 = blockIdx.x * 64;
    const int n0 = blockIdx.y * 64;
    const int t  = threadIdx.x;
    const int tx = t & 15, ty = t >> 4;
    const int sm = t >> 2;          // staging row 0..63
    const int sq = (t & 3) * 4;     // staging k-quad

    float acc[4][4];
#pragma unroll
    for (int i = 0; i < 4; i++)
#pragma unroll
        for (int j = 0; j < 4; j++) acc[i][j] = 0.f;

    for (int k0 = 0; k0 < K; k0 += 16) {
        {   // stage A (M multiple of 64)
            const int m = m0 + sm;
            const float4 av = *(const float4*)(A + (size_t)m * lda + acol + k0 + sq);
            As[sq + 0][sm] = av.x; As[sq + 1][sm] = av.y;
            As[sq + 2][sm] = av.z; As[sq + 3][sm] = av.w;
        }
        {   // stage B
            const int n = n0 + sm;
            float4 bv = make_float4(0.f, 0.f, 0.f, 0.f);
            if (n < N) bv = *(const float4*)(B + (size_t)n * ldb + bcol + k0 + sq);
            Bs[sq + 0][sm] = bv.x; Bs[sq + 1][sm] = bv.y;
            Bs[sq + 2][sm] = bv.z; Bs[sq + 3][sm] = bv.w;
        }
        __syncthreads();
#pragma unroll
        for (int kk = 0; kk < 16; kk++) {
            const float4 a = *(const float4*)&As[kk][ty * 4];
            const float4 b = *(const float4*)&Bs[kk][tx * 4];
            const float av2[4] = {a.x, a.y, a.z, a.w};
            const float bv2[4] = {b.x, b.y, b.z, b.w};
#pragma unroll
            for (int i = 0; i < 4; i++)
#pragma unroll
                for (int j = 0; j < 4; j++) acc[i][j] += av2[i] * bv2[j];
        }
        __syncthreads();
    }

    const int nbase = n0 + tx * 4;
    if (nbase >= N) return;
#pragma unroll
    for (int i = 0; i < 4; i++) {
        const int m = m0 + ty * 4 + i;
        float4 r = make_float4(acc[i][0], acc[i][1], acc[i][2], acc[i][3]);
        if constexpr (EPI == EPI_DEC) {
            const float4 bb = *(const float4*)(bias + nbase);
            r.x = expf(-expf(r.x + bb.x));
            r.y = expf(-expf(r.y + bb.y));
            r.z = expf(-expf(r.z + bb.z));
            r.w = expf(-expf(r.w + bb.w));
        } else if constexpr (EPI == EPI_LERP) {
            const float4 bb = *(const float4*)(bias + nbase);
            const float4 xv = *(const float4*)(xsrc + (size_t)m * H + nbase);
            float4 pv = make_float4(0.f, 0.f, 0.f, 0.f);
            if ((m & (LSEQ - 1)) != 0)
                pv = *(const float4*)(xsrc + (size_t)(m - 1) * H + nbase);
            r.x = xv.x + (pv.x - xv.x) * (r.x + bb.x);
            r.y = xv.y + (pv.y - xv.y) * (r.y + bb.y);
            r.z = xv.z + (pv.z - xv.z) * (r.z + bb.z);
            r.w = xv.w + (pv.w - xv.w) * (r.w + bb.w);
        }
        if (Cf) *(float4*)(Cf + (size_t)m * ldc + nbase) = r;
        if (C2) {
            ushort4 p;
            p.x = f2h(r.x); p.y = f2h(r.y); p.z = f2h(r.z); p.w = f2h(r.w);
            *(ushort4*)(C2 + (size_t)m * ldc + nbase) = p;
        }
    }
}

// ---------------------------------------------------------------------------
// fp16 MFMA GEMM (m97 structure): C[m][n] = sum_k A[m][k] * B[n][k], f32 out.
// A2/nsplit: blocks with n0 >= nsplit read A2 (fused r|k and v|g launches).
// EPI_TANH applies tanh in the epilogue (xp / wlow LoRA-down).
// ---------------------------------------------------------------------------
template<int EPI>
__global__ __launch_bounds__(256) void gemm_mfma_bt(
    const unsigned short* __restrict__ A,
    const unsigned short* __restrict__ A2, int nsplit, int lda,
    const unsigned short* __restrict__ B, int ldb,
    float* __restrict__ C, int ldc, int K)
{
    __shared__ __align__(16) unsigned short As[128 * 32];
    __shared__ __align__(16) unsigned short Bs[128 * 32];
    const int t    = threadIdx.x;
    const int w    = t >> 6;
    const int lane = t & 63;
    const int m0 = blockIdx.x * 128;
    const int n0 = blockIdx.y * 128;
    const unsigned short* Au = (n0 < nsplit) ? A : A2;
    const int mw = (w & 1) * 64;
    const int nw = (w >> 1) * 64;
    const int l15 = lane & 15;
    const int q4  = lane >> 4;

    f32x4 acc[4][4];
#pragma unroll
    for (int i = 0; i < 4; i++)
#pragma unroll
        for (int j = 0; j < 4; j++) {
            f32x4 z = {0.f, 0.f, 0.f, 0.f};
            acc[i][j] = z;
        }

    for (int k0 = 0; k0 < K; k0 += 32) {
        __syncthreads();
#pragma unroll
        for (int jj = 0; jj < 2; jj++) {
            const int c   = w * 128 + jj * 64 + lane;   // 16B chunk id
            const int row = c >> 2;
            const int col = (c & 3) * 8;
            __builtin_amdgcn_global_load_lds(
                (const __attribute__((address_space(1))) void*)(Au + (size_t)(m0 + row) * lda + k0 + col),
                (__attribute__((address_space(3))) void*)((char*)As + (w * 128 + jj * 64) * 16),
                16, 0, 0);
            __builtin_amdgcn_global_load_lds(
                (const __attribute__((address_space(1))) void*)(B + (size_t)(n0 + row) * ldb + k0 + col),
                (__attribute__((address_space(3))) void*)((char*)Bs + (w * 128 + jj * 64) * 16),
                16, 0, 0);
        }
        __syncthreads();

        half8 a[4], b[4];
#pragma unroll
        for (int i = 0; i < 4; i++)
            a[i] = *(const half8*)(As + (mw + i * 16 + l15) * 32 + q4 * 8);
#pragma unroll
        for (int j = 0; j < 4; j++)
            b[j] = *(const half8*)(Bs + (nw + j * 16 + l15) * 32 + q4 * 8);
#pragma unroll
        for (int i = 0; i < 4; i++)
#pragma unroll
            for (int j = 0; j < 4; j++)
                acc[i][j] = __builtin_amdgcn_mfma_f32_16x16x32_f16(a[i], b[j], acc[i][j], 0, 0, 0);
    }

#pragma unroll
    for (int i = 0; i < 4; i++) {
        const int m_base = m0 + mw + i * 16 + q4 * 4;
#pragma unroll
        for (int j = 0; j < 4; j++) {
            const int n = n0 + nw + j * 16 + l15;
#pragma unroll
            for (int r = 0; r < 4; r++) {
                float val = acc[i][j][r];
                if constexpr (EPI == EPI_TANH) val = tanhf(val);
                C[(size_t)(m_base + r) * ldc + n] = val;
            }
        }
    }
}

// ---------------------------------------------------------------------------
// Batched fp16 MFMA GEMM with C-accumulate (scan correction):
// o[seg,bh][m,n] += sum_k rt16[m,k] * SentryT16[n,k].  M=N=256, K=128.
// ---------------------------------------------------------------------------
__global__ __launch_bounds__(256) void gemm_mfma_corr(
    const unsigned short* __restrict__ rt16,
    const unsigned short* __restrict__ SentryT16,
    float* __restrict__ o)
{
    const int z   = blockIdx.z;
    const int seg = (z >> 3) + 1;
    const int bh  = z & 7;
    const int b   = bh >> 2, h = bh & 3;
    const unsigned short* A = rt16 + ((size_t)b * LSEQ + seg * SEGL) * KDIM + h * DKK;
    const unsigned short* B = SentryT16 + (size_t)(seg * 8 + bh) * 32768;
    float* C = o + ((size_t)b * LSEQ + seg * SEGL) * VDIM + h * DVV;

    __shared__ __align__(16) unsigned short As[128 * 32];
    __shared__ __align__(16) unsigned short Bs[128 * 32];
    const int t    = threadIdx.x;
    const int w    = t >> 6;
    const int lane = t & 63;
    const int m0 = blockIdx.x * 128;
    const int n0 = blockIdx.y * 128;
    const int mw = (w & 1) * 64;
    const int nw = (w >> 1) * 64;
    const int l15 = lane & 15;
    const int q4  = lane >> 4;

    f32x4 acc[4][4];
#pragma unroll
    for (int i = 0; i < 4; i++)
#pragma unroll
        for (int j = 0; j < 4; j++) {
            f32x4 zz = {0.f, 0.f, 0.f, 0.f};
            acc[i][j] = zz;
        }

    for (int k0 = 0; k0 < 128; k0 += 32) {
        __syncthreads();
#pragma unroll
        for (int jj = 0; jj < 2; jj++) {
            const int c   = w * 128 + jj * 64 + lane;
            const int row = c >> 2;
            const int col = (c & 3) * 8;
            __builtin_amdgcn_global_load_lds(
                (const __attribute__((address_space(1))) void*)(A + (size_t)(m0 + row) * KDIM + k0 + col),
                (__attribute__((address_space(3))) void*)((char*)As + (w * 128 + jj * 64) * 16),
                16, 0, 0);
            __builtin_amdgcn_global_load_lds(
                (const __attribute__((address_space(1))) void*)(B + (size_t)(n0 + row) * 128 + k0 + col),
                (__attribute__((address_space(3))) void*)((char*)Bs + (w * 128 + jj * 64) * 16),
                16, 0, 0);
        }
        __syncthreads();

        half8 a[4], bb[4];
#pragma unroll
        for (int i = 0; i < 4; i++)
            a[i] = *(const half8*)(As + (mw + i * 16 + l15) * 32 + q4 * 8);
#pragma unroll
        for (int j = 0; j < 4; j++)
            bb[j] = *(const half8*)(Bs + (nw + j * 16 + l15) * 32 + q4 * 8);
#pragma unroll
        for (int i = 0; i < 4; i++)
#pragma unroll
            for (int j = 0; j < 4; j++)
                acc[i][j] = __builtin_amdgcn_mfma_f32_16x16x32_f16(a[i], bb[j], acc[i][j], 0, 0, 0);
    }

#pragma unroll
    for (int i = 0; i < 4; i++) {
        const int m_base = m0 + mw + i * 16 + q4 * 4;
#pragma unroll
        for (int j = 0; j < 4; j++) {
            const int n = n0 + nw + j * 16 + l15;
#pragma unroll
            for (int rr = 0; rr < 4; rr++)
                C[(size_t)(m_base + rr) * VDIM + n] += acc[i][j][rr];
        }
    }
}

// ---------------------------------------------------------------------------
// Weight pack: Wr|Wk|Wv|Wg|Wo fp16 + zero-padded Wx1 (256x1024) + Ww1 (128x1024)
// ---------------------------------------------------------------------------
__global__ __launch_bounds__(256) void cvt_weights(
    const float* __restrict__ Wr, const float* __restrict__ Wk,
    const float* __restrict__ Wv, const float* __restrict__ Wg,
    const float* __restrict__ Wo, const float* __restrict__ Wx1,
    const float* __restrict__ Ww1,
    unsigned short* __restrict__ Wb, unsigned short* __restrict__ Wx1p,
    unsigned short* __restrict__ Ww1p)
{
    const int q = blockIdx.x * 256 + threadIdx.x;   // quad index
    float4 v = make_float4(0.f, 0.f, 0.f, 0.f);
    unsigned short* dst;
    if (q < 1048576) {
        const int i4 = q * 4;
        const float* src; int off;
        if      (i4 <  524288) { src = Wr; off = i4; }
        else if (i4 < 1048576) { src = Wk; off = i4 -  524288; }
        else if (i4 < 2097152) { src = Wv; off = i4 - 1048576; }
        else if (i4 < 3145728) { src = Wg; off = i4 - 2097152; }
        else                   { src = Wo; off = i4 - 3145728; }
        v = *(const float4*)(src + off);
        dst = Wb + i4;
    } else if (q < 1114112) {
        const int e = (q - 1048576) * 4;
        const int row = e >> 10;
        if (row < 160) v = *(const float4*)(Wx1 + (size_t)row * H + (e & 1023));
        dst = Wx1p + e;
    } else {
        const int e = (q - 1114112) * 4;
        const int row = e >> 10;
        if (row < 64) v = *(const float4*)(Ww1 + (size_t)row * H + (e & 1023));
        dst = Ww1p + e;
    }
    ushort4 o4;
    o4.x = f2h(v.x); o4.y = f2h(v.y); o4.z = f2h(v.z); o4.w = f2h(v.w);
    *(ushort4*)dst = o4;
}

// ---------------------------------------------------------------------------
// xl = x + (shift(x) - x) * mu_x  -> fp16   (one block per row)
// ---------------------------------------------------------------------------
__global__ __launch_bounds__(256) void xl_kernel(
    const float* __restrict__ x, const float* __restrict__ mux,
    unsigned short* __restrict__ xl16)
{
    const int m = blockIdx.x;
    const int c = threadIdx.x * 4;
    const float4 xv = *(const float4*)(x + (size_t)m * H + c);
    float4 pv = make_float4(0.f, 0.f, 0.f, 0.f);
    if ((m & (LSEQ - 1)) != 0)
        pv = *(const float4*)(x + (size_t)(m - 1) * H + c);
    const float4 mv = *(const float4*)(mux + c);
    ushort4 p;
    p.x = f2h(xv.x + (pv.x - xv.x) * mv.x);
    p.y = f2h(xv.y + (pv.y - xv.y) * mv.y);
    p.z = f2h(xv.z + (pv.z - xv.z) * mv.z);
    p.w = f2h(xv.w + (pv.w - xv.w) * mv.w);
    *(ushort4*)(xl16 + (size_t)m * H + c) = p;
}

// ---------------------------------------------------------------------------
// Scan pass 1 v4: segmented recurrence, 64-VGPR cap -> 8 blocks/CU resident.
// 2048 blocks = (seg, bh, vchunk of 8). CHUNK=2 synchronous loads; DPP reduce.
// rk: fused [r|k] buffer ld 1024; vg: fused [v|g] ld 2048.
// ---------------------------------------------------------------------------
__global__ __launch_bounds__(256, 8) void scan_pass1(
    const float* __restrict__ rk, const float* __restrict__ vg,
    const float* __restrict__ dec, const float* __restrict__ bonus,
    float* __restrict__ o, unsigned short* __restrict__ rt16,
    float* __restrict__ Sloc, float* __restrict__ Dtot)
{
    const int vc  = blockIdx.x & 31;
    const int bh  = (blockIdx.x >> 5) & 7;
    const int seg = blockIdx.x >> 8;
    const int b   = bh >> 2;
    const int h   = bh & 3;
    const int t   = threadIdx.x;
    const int kg  = t & 31;
    const int vl  = t >> 5;
    const bool wlead = (vc == 0) && (vl == 0);

    float S[4] = {0.f, 0.f, 0.f, 0.f}, D[4] = {1.f, 1.f, 1.f, 1.f}, u[4];
#pragma unroll
    for (int j = 0; j < 4; j++) u[j] = bonus[h * DKK + kg * 4 + j];

    const size_t row0 = (size_t)b * LSEQ + (size_t)seg * SEGL;
    const float* rp = rk  + row0 * 1024 + h * DKK + kg * 4;
    const float* kp = rp + 512;
    const float* dp = dec + row0 * 512 + h * DKK + kg * 4;
    const float* vp = vg  + row0 * 2048 + h * DVV + vc * 8 + vl;
    float*       op = o   + row0 * 1024 + h * DVV + vc * 8 + vl;
    unsigned short* rt = rt16 + row0 * 512 + h * DKK + kg * 4;

    for (int t0 = 0; t0 < SEGL; t0 += 2) {
        const float4 r0 = *(const float4*)rp;
        const float4 r1 = *(const float4*)(rp + 1024);
        const float4 k0 = *(const float4*)kp;
        const float4 k1 = *(const float4*)(kp + 1024);
        const float4 d0 = *(const float4*)dp;
        const float4 d1 = *(const float4*)(dp + 512);
        const float  v0 = vp[0];
        const float  v1 = vp[2048];
        rp += 2048; kp += 2048; dp += 1024; vp += 4096;

        // ---- step 0
        if (wlead) {
            ushort4 p;
            p.x = f2h(r0.x * D[0]); p.y = f2h(r0.y * D[1]);
            p.z = f2h(r0.z * D[2]); p.w = f2h(r0.w * D[3]);
            *(ushort4*)rt = p;
        }
        {
            float kv, tmp, part;
            kv = k0.x * v0; tmp = fmaf(u[0], kv, S[0]); part = r0.x * tmp;            S[0] = fmaf(d0.x, S[0], kv);
            kv = k0.y * v0; tmp = fmaf(u[1], kv, S[1]); part = fmaf(r0.y, tmp, part); S[1] = fmaf(d0.y, S[1], kv);
            kv = k0.z * v0; tmp = fmaf(u[2], kv, S[2]); part = fmaf(r0.z, tmp, part); S[2] = fmaf(d0.z, S[2], kv);
            kv = k0.w * v0; tmp = fmaf(u[3], kv, S[3]); part = fmaf(r0.w, tmp, part); S[3] = fmaf(d0.w, S[3], kv);
            D[0] *= d0.x; D[1] *= d0.y; D[2] *= d0.z; D[3] *= d0.w;
            part = dpp_add<0xB1>(part);
            part = dpp_add<0x4E>(part);
            part = dpp_add<0x141>(part);
            part = dpp_add<0x140>(part);
            part = dpp_add<0x142>(part);
            if (kg == 31) op[0] = part;
        }
        // ---- step 1
        if (wlead) {
            ushort4 p;
            p.x = f2h(r1.x * D[0]); p.y = f2h(r1.y * D[1]);
            p.z = f2h(r1.z * D[2]); p.w = f2h(r1.w * D[3]);
            *(ushort4*)(rt + 512) = p;
        }
        {
            float kv, tmp, part;
            kv = k1.x * v1; tmp = fmaf(u[0], kv, S[0]); part = r1.x * tmp;            S[0] = fmaf(d1.x, S[0], kv);
            kv = k1.y * v1; tmp = fmaf(u[1], kv, S[1]); part = fmaf(r1.y, tmp, part); S[1] = fmaf(d1.y, S[1], kv);
            kv = k1.z * v1; tmp = fmaf(u[2], kv, S[2]); part = fmaf(r1.z, tmp, part); S[2] = fmaf(d1.z, S[2], kv);
            kv = k1.w * v1; tmp = fmaf(u[3], kv, S[3]); part = fmaf(r1.w, tmp, part); S[3] = fmaf(d1.w, S[3], kv);
            D[0] *= d1.x; D[1] *= d1.y; D[2] *= d1.z; D[3] *= d1.w;
            part = dpp_add<0xB1>(part);
            part = dpp_add<0x4E>(part);
            part = dpp_add<0x141>(part);
            part = dpp_add<0x140>(part);
            part = dpp_add<0x142>(part);
            if (kg == 31) op[1024] = part;
        }
        op += 2048; rt += 1024;
    }

    {
        float* sl = Sloc + (size_t)(seg * 8 + bh) * 32768 + (size_t)(kg * 4) * 256 + vc * 8 + vl;
#pragma unroll
        for (int j = 0; j < 4; j++) sl[j * 256] = S[j];
        if (wlead) {
            float* dt = Dtot + (seg * 8 + bh) * 128 + kg * 4;
#pragma unroll
            for (int j = 0; j < 4; j++) dt[j] = D[j];
        }
    }
}

// ---------------------------------------------------------------------------
// Scan pass 2: propagate entry states across segments; Sentry^T as fp16.
// ---------------------------------------------------------------------------
__global__ __launch_bounds__(256) void scan_pass2(
    const float* __restrict__ Sloc, const float* __restrict__ Dtot,
    unsigned short* __restrict__ SentryT16)
{
    const int vc = blockIdx.x & 31;
    const int bh = blockIdx.x >> 5;
    const int t  = threadIdx.x;
    const int kg = t & 31;
    const int vl = t >> 5;

    float S[4] = {0.f, 0.f, 0.f, 0.f};
    for (int p = 0; p < NSEG; p++) {
        unsigned short* st = SentryT16 + (size_t)(p * 8 + bh) * 32768
                             + (size_t)(vc * 8 + vl) * 128 + kg * 4;
        ushort4 pk;
        pk.x = f2h(S[0]); pk.y = f2h(S[1]); pk.z = f2h(S[2]); pk.w = f2h(S[3]);
        *(ushort4*)st = pk;
        if (p < NSEG - 1) {
            const float* sl = Sloc + (size_t)(p * 8 + bh) * 32768
                              + (size_t)(kg * 4) * 256 + vc * 8 + vl;
            const float* dt = Dtot + (p * 8 + bh) * 128 + kg * 4;
#pragma unroll
            for (int j = 0; j < 4; j++) S[j] = dt[j] * S[j] + sl[j * 256];
        }
    }
}

// ---------------------------------------------------------------------------
// Per-head LayerNorm + swish gate -> fp16. g lives in the fused vg buffer.
// ---------------------------------------------------------------------------
__global__ __launch_bounds__(256) void ln_gate_kernel(
    const float* __restrict__ o, const float* __restrict__ vg,
    const float* __restrict__ lnw, const float* __restrict__ lnb,
    unsigned short* __restrict__ out)
{
    const int m    = blockIdx.x;
    const int t    = threadIdx.x;
    const int h    = t >> 6;
    const int lane = t & 63;
    const size_t obase = (size_t)m * VDIM + (size_t)h * DVV + lane * 4;
    const size_t gbase = (size_t)m * 2048 + 1024 + (size_t)h * DVV + lane * 4;
    const float4 ov = *(const float4*)(o + obase);
    float sum = ov.x + ov.y + ov.z + ov.w;
    float sq  = ov.x * ov.x + ov.y * ov.y + ov.z * ov.z + ov.w * ov.w;
#pragma unroll
    for (int off = 1; off < 64; off <<= 1) {
        sum += __shfl_xor(sum, off);
        sq  += __shfl_xor(sq, off);
    }
    const float mean = sum * (1.f / DVV);
    const float var  = sq * (1.f / DVV) - mean * mean;
    const float rstd = rsqrtf(var + 1e-5f);
    const float4 gv = *(const float4*)(vg + gbase);
    const float4 wv = *(const float4*)(lnw + lane * 4);
    const float4 bv = *(const float4*)(lnb + lane * 4);
    float4 res;
    res.x = ((ov.x - mean) * rstd * wv.x + bv.x) * (gv.x / (1.f + expf(-gv.x)));
    res.y = ((ov.y - mean) * rstd * wv.y + bv.y) * (gv.y / (1.f + expf(-gv.y)));
    res.z = ((ov.z - mean) * rstd * wv.z + bv.z) * (gv.z / (1.f + expf(-gv.z)));
    res.w = ((ov.w - mean) * rstd * wv.w + bv.w) * (gv.w / (1.f + expf(-gv.w)));
    ushort4 p;
    p.x = f2h(res.x); p.y = f2h(res.y); p.z = f2h(res.z); p.w = f2h(res.w);
    *(ushort4*)(out + obase) = p;
}

extern "C" void kernel_launch(void* const* d_in, const int* in_sizes, int n_in,
                              void* d_out, int out_size, void* d_ws, size_t ws_size,
                              hipStream_t stream)
{
    const float* x     = (const float*)d_in[0];
    const float* mu_x  = (const float*)d_in[1];
    const float* Wx1   = (const float*)d_in[2];
    const float* Wx2   = (const float*)d_in[3];
    const float* xb    = (const float*)d_in[4];
    const float* Wr    = (const float*)d_in[5];
    const float* Wk    = (const float*)d_in[6];
    const float* Wv    = (const float*)d_in[7];
    const float* Wg    = (const float*)d_in[8];
    const float* Ww1   = (const float*)d_in[9];
    const float* Ww2   = (const float*)d_in[10];
    const float* bw2   = (const float*)d_in[11];
    const float* bonus = (const float*)d_in[12];
    const float* lnw   = (const float*)d_in[13];
    const float* lnb   = (const float*)d_in[14];
    const float* Wo    = (const float*)d_in[15];
    float* out = (float*)d_out;
    (void)in_sizes; (void)n_in; (void)out_size; (void)ws_size;

    float* ws = (float*)d_ws;
    // layout (f32 word offsets)
    unsigned short* Wx1p = (unsigned short*)(ws + 0);         // 256x1024 fp16
    unsigned short* Ww1p = (unsigned short*)(ws + 131072);    // 128x1024 fp16
    unsigned short* Wb   = (unsigned short*)(ws + 196608);    // 5 packed weights fp16
    float* xp    = ws + 2293760;                              // 4096x256 f32
    float* insB  = ws + 3342336;                              // 5 fp16 slots x 2097152 words
    float* rkB   = ws + 13828096;                             // 4096x1024 f32
    float* vgB   = ws + 18022400;                             // 4096x2048 f32
    float* wlow  = ws + 26411008;                             // 4096x128 f32
    float* decB  = ws + 26935296;                             // 4096x512 f32

    unsigned short* insb = (unsigned short*)insB;             // slot n: insb + n*4194304
    unsigned short* Wrb  = Wb;                                // rows 0-1023 = [Wr;Wk]
    unsigned short* Wvb  = Wb + 1048576;                      // rows 0-2047 = [Wv;Wg]
    unsigned short* Wob  = Wb + 3145728;
    unsigned short* xl16 = (unsigned short*)rkB;              // dead before rk GEMM writes
    // scan-time aliases over consumed fp16 slots
    float*          o       = insB;                                   // slots 0,1
    unsigned short* rt16    = insb + 2ul * 4194304;                   // slot 2
    float*          Sloc    = insB + 3ul * 2097152;                   // slot 3
    unsigned short* gatedb  = (unsigned short*)(insB + 3ul * 2097152);// slot 3 (after Sloc dead)
    float*          Dtot    = insB + 4ul * 2097152;                   // slot 4
    unsigned short* SentryT16 = (unsigned short*)(Dtot + 8192);       // slot 4

    dim3 blk(256);

    cvt_weights<<<dim3(4480), blk, 0, stream>>>(Wr, Wk, Wv, Wg, Wo, Wx1, Ww1,
                                                Wb, Wx1p, Ww1p);
    xl_kernel<<<dim3(4096), blk, 0, stream>>>(x, mu_x, xl16);

    // xp = tanh(xl @ Wx1p^T)  [4096 x 256 f32, cols 160.. are zero]
    gemm_mfma_bt<EPI_TANH><<<dim3(32, 2), blk, 0, stream>>>(
        xl16, xl16, 1 << 30, H, Wx1p, H, xp, 256, H);

    // fused thin-K: in_n = x + delta*(xp_n @ Wx2_n^T + x_bias_n) -> fp16 slot n
    gemm_bt<EPI_LERP><<<dim3(64, 16, 5), blk, 0, stream>>>(
        xp, 256, 0, Wx2, 160, 0, nullptr, insb, H, MTOT, H, 32, x, xb);

    // wlow = tanh(in_w16 @ Ww1p^T)  [4096 x 128 f32, cols 64.. zero]
    gemm_mfma_bt<EPI_TANH><<<dim3(32, 1), blk, 0, stream>>>(
        insb + 1ul * 4194304, insb + 1ul * 4194304, 1 << 30, H, Ww1p, H, wlow, 128, H);

    // dec = exp(-exp(wlow @ Ww2^T + bw2))  (f32 VALU, K=64)
    gemm_bt<EPI_DEC><<<dim3(64, 8), blk, 0, stream>>>(
        wlow, 128, 0, Ww2, GRR, 0, decB, nullptr, KDIM, MTOT, KDIM, GRR, nullptr, bw2);

    // fused projections: rk = [r|k] (N=1024), vg = [v|g] (N=2048)
    gemm_mfma_bt<EPI_NONE><<<dim3(32, 8), blk, 0, stream>>>(
        insb + 0ul * 4194304, insb + 2ul * 4194304, 512, H, Wrb, H, rkB, 1024, H);
    gemm_mfma_bt<EPI_NONE><<<dim3(32, 16), blk, 0, stream>>>(
        insb + 3ul * 4194304, insb + 4ul * 4194304, 1024, H, Wvb, H, vgB, 2048, H);

    // segmented RWKV scan
    scan_pass1<<<dim3(2048), blk, 0, stream>>>(rkB, vgB, decB, bonus, o, rt16, Sloc, Dtot);
    scan_pass2<<<dim3(256), blk, 0, stream>>>(Sloc, Dtot, SentryT16);
    gemm_mfma_corr<<<dim3(2, 2, 56), blk, 0, stream>>>(rt16, SentryT16, o);

    // per-head LN + swish gate -> fp16 gated
    ln_gate_kernel<<<dim3(4096), blk, 0, stream>>>(o, vgB, lnw, lnb, gatedb);

    // out = gated @ Wo^T
    gemm_mfma_bt<EPI_NONE><<<dim3(32, 8), blk, 0, stream>>>(
        gatedb, gatedb, 1 << 30, VDIM, Wob, VDIM, out, H, VDIM);
}

// Round 7
// 487.510 us; speedup vs baseline: 3.6868x; 1.1405x over previous
//
#include <hip/hip_runtime.h>
#include <cstdint>
#include <cstddef>

#define H     1024
#define LSEQ  2048
#define NHH   4
#define DKK   128
#define DVV   256
#define KDIM  512
#define VDIM  1024
#define GRR   64
#define MTOT  4096   // B*L
#define SEGL  256    // scan segment length
#define NSEG  8

enum { EPI_NONE = 0, EPI_TANH = 1, EPI_LERP = 2, EPI_DEC = 3 };

typedef __attribute__((ext_vector_type(8))) _Float16 half8;
typedef __attribute__((ext_vector_type(4))) float f32x4;

static __device__ __forceinline__ unsigned short f2h(float f) {
    _Float16 h = (_Float16)f;          // v_cvt_f16_f32, RNE
    union { _Float16 h; unsigned short u; } c;
    c.h = h;
    return c.u;
}

// DPP-based partial-wave reduction step: return x + dpp_move(x, CTRL). Pure VALU.
template<int CTRL>
static __device__ __forceinline__ float dpp_add(float x) {
    int xi = __float_as_int(x);
    int mv = __builtin_amdgcn_update_dpp(0, xi, CTRL, 0xf, 0xf, true);
    return x + __int_as_float(mv);
}

// ---------------------------------------------------------------------------
// f32 VALU GEMM: C[m][n] = sum_k A[m][k+acol]*B[n][k+bcol]
// EPI_LERP instantiation is the fused 5-way thin-K kernel: blockIdx.z picks
// the mixing branch (acol/bcol += z*32, bias += z*H, C2 += z*slot).
// ---------------------------------------------------------------------------
template<int EPI>
__global__ __launch_bounds__(256) void gemm_bt(
    const float* __restrict__ A, int lda, int acol,
    const float* __restrict__ B, int ldb, int bcol,
    float* __restrict__ Cf, unsigned short* __restrict__ C2, int ldc,
    int M, int N, int K,
    const float* __restrict__ xsrc,   // LERP epilogue source (ld = H)
    const float* __restrict__ bias)   // LERP: x_bias row; DEC: bw2
{
    if constexpr (EPI == EPI_LERP) {
        const int zz = blockIdx.z;
        acol += zz * 32;
        bcol += zz * 32;
        bias += zz * H;
        C2   += (size_t)zz * 4194304;   // fp16 slot stride
    }
    __shared__ float As[16][64];
    __shared__ float Bs[16][64];
    const int m0 = blockIdx.x * 64;
    const int n0 = blockIdx.y * 64;
    const int t  = threadIdx.x;
    const int tx = t & 15, ty = t >> 4;
    const int sm = t >> 2;          // staging row 0..63
    const int sq = (t & 3) * 4;     // staging k-quad

    float acc[4][4];
#pragma unroll
    for (int i = 0; i < 4; i++)
#pragma unroll
        for (int j = 0; j < 4; j++) acc[i][j] = 0.f;

    for (int k0 = 0; k0 < K; k0 += 16) {
        {   // stage A (M multiple of 64)
            const int m = m0 + sm;
            const float4 av = *(const float4*)(A + (size_t)m * lda + acol + k0 + sq);
            As[sq + 0][sm] = av.x; As[sq + 1][sm] = av.y;
            As[sq + 2][sm] = av.z; As[sq + 3][sm] = av.w;
        }
        {   // stage B
            const int n = n0 + sm;
            float4 bv = make_float4(0.f, 0.f, 0.f, 0.f);
            if (n < N) bv = *(const float4*)(B + (size_t)n * ldb + bcol + k0 + sq);
            Bs[sq + 0][sm] = bv.x; Bs[sq + 1][sm] = bv.y;
            Bs[sq + 2][sm] = bv.z; Bs[sq + 3][sm] = bv.w;
        }
        __syncthreads();
#pragma unroll
        for (int kk = 0; kk < 16; kk++) {
            const float4 a = *(const float4*)&As[kk][ty * 4];
            const float4 b = *(const float4*)&Bs[kk][tx * 4];
            const float av2[4] = {a.x, a.y, a.z, a.w};
            const float bv2[4] = {b.x, b.y, b.z, b.w};
#pragma unroll
            for (int i = 0; i < 4; i++)
#pragma unroll
                for (int j = 0; j < 4; j++) acc[i][j] += av2[i] * bv2[j];
        }
        __syncthreads();
    }

    const int nbase = n0 + tx * 4;
    if (nbase >= N) return;
#pragma unroll
    for (int i = 0; i < 4; i++) {
        const int m = m0 + ty * 4 + i;
        float4 r = make_float4(acc[i][0], acc[i][1], acc[i][2], acc[i][3]);
        if constexpr (EPI == EPI_DEC) {
            const float4 bb = *(const float4*)(bias + nbase);
            r.x = expf(-expf(r.x + bb.x));
            r.y = expf(-expf(r.y + bb.y));
            r.z = expf(-expf(r.z + bb.z));
            r.w = expf(-expf(r.w + bb.w));
        } else if constexpr (EPI == EPI_LERP) {
            const float4 bb = *(const float4*)(bias + nbase);
            const float4 xv = *(const float4*)(xsrc + (size_t)m * H + nbase);
            float4 pv = make_float4(0.f, 0.f, 0.f, 0.f);
            if ((m & (LSEQ - 1)) != 0)
                pv = *(const float4*)(xsrc + (size_t)(m - 1) * H + nbase);
            r.x = xv.x + (pv.x - xv.x) * (r.x + bb.x);
            r.y = xv.y + (pv.y - xv.y) * (r.y + bb.y);
            r.z = xv.z + (pv.z - xv.z) * (r.z + bb.z);
            r.w = xv.w + (pv.w - xv.w) * (r.w + bb.w);
        }
        if (Cf) *(float4*)(Cf + (size_t)m * ldc + nbase) = r;
        if (C2) {
            ushort4 p;
            p.x = f2h(r.x); p.y = f2h(r.y); p.z = f2h(r.z); p.w = f2h(r.w);
            *(ushort4*)(C2 + (size_t)m * ldc + nbase) = p;
        }
    }
}

// ---------------------------------------------------------------------------
// fp16 MFMA GEMM (m97 structure): C[m][n] = sum_k A[m][k] * B[n][k], f32 out.
// A2/nsplit: blocks with n0 >= nsplit read A2 (fused r|k and v|g launches).
// EPI_TANH applies tanh in the epilogue (xp / wlow LoRA-down).
// ---------------------------------------------------------------------------
template<int EPI>
__global__ __launch_bounds__(256) void gemm_mfma_bt(
    const unsigned short* __restrict__ A,
    const unsigned short* __restrict__ A2, int nsplit, int lda,
    const unsigned short* __restrict__ B, int ldb,
    float* __restrict__ C, int ldc, int K)
{
    __shared__ __align__(16) unsigned short As[128 * 32];
    __shared__ __align__(16) unsigned short Bs[128 * 32];
    const int t    = threadIdx.x;
    const int w    = t >> 6;
    const int lane = t & 63;
    const int m0 = blockIdx.x * 128;
    const int n0 = blockIdx.y * 128;
    const unsigned short* Au = (n0 < nsplit) ? A : A2;
    const int mw = (w & 1) * 64;
    const int nw = (w >> 1) * 64;
    const int l15 = lane & 15;
    const int q4  = lane >> 4;

    f32x4 acc[4][4];
#pragma unroll
    for (int i = 0; i < 4; i++)
#pragma unroll
        for (int j = 0; j < 4; j++) {
            f32x4 z = {0.f, 0.f, 0.f, 0.f};
            acc[i][j] = z;
        }

    for (int k0 = 0; k0 < K; k0 += 32) {
        __syncthreads();
#pragma unroll
        for (int jj = 0; jj < 2; jj++) {
            const int c   = w * 128 + jj * 64 + lane;   // 16B chunk id
            const int row = c >> 2;
            const int col = (c & 3) * 8;
            __builtin_amdgcn_global_load_lds(
                (const __attribute__((address_space(1))) void*)(Au + (size_t)(m0 + row) * lda + k0 + col),
                (__attribute__((address_space(3))) void*)((char*)As + (w * 128 + jj * 64) * 16),
                16, 0, 0);
            __builtin_amdgcn_global_load_lds(
                (const __attribute__((address_space(1))) void*)(B + (size_t)(n0 + row) * ldb + k0 + col),
                (__attribute__((address_space(3))) void*)((char*)Bs + (w * 128 + jj * 64) * 16),
                16, 0, 0);
        }
        __syncthreads();

        half8 a[4], b[4];
#pragma unroll
        for (int i = 0; i < 4; i++)
            a[i] = *(const half8*)(As + (mw + i * 16 + l15) * 32 + q4 * 8);
#pragma unroll
        for (int j = 0; j < 4; j++)
            b[j] = *(const half8*)(Bs + (nw + j * 16 + l15) * 32 + q4 * 8);
#pragma unroll
        for (int i = 0; i < 4; i++)
#pragma unroll
            for (int j = 0; j < 4; j++)
                acc[i][j] = __builtin_amdgcn_mfma_f32_16x16x32_f16(a[i], b[j], acc[i][j], 0, 0, 0);
    }

#pragma unroll
    for (int i = 0; i < 4; i++) {
        const int m_base = m0 + mw + i * 16 + q4 * 4;
#pragma unroll
        for (int j = 0; j < 4; j++) {
            const int n = n0 + nw + j * 16 + l15;
#pragma unroll
            for (int r = 0; r < 4; r++) {
                float val = acc[i][j][r];
                if constexpr (EPI == EPI_TANH) val = tanhf(val);
                C[(size_t)(m_base + r) * ldc + n] = val;
            }
        }
    }
}

// ---------------------------------------------------------------------------
// Batched fp16 MFMA GEMM with C-accumulate (scan correction):
// o[seg,bh][m,n] += sum_k rt16[m,k] * SentryT16[n,k].  M=N=256, K=128.
// ---------------------------------------------------------------------------
__global__ __launch_bounds__(256) void gemm_mfma_corr(
    const unsigned short* __restrict__ rt16,
    const unsigned short* __restrict__ SentryT16,
    float* __restrict__ o)
{
    const int z   = blockIdx.z;
    const int seg = (z >> 3) + 1;
    const int bh  = z & 7;
    const int b   = bh >> 2, h = bh & 3;
    const unsigned short* A = rt16 + ((size_t)b * LSEQ + seg * SEGL) * KDIM + h * DKK;
    const unsigned short* B = SentryT16 + (size_t)(seg * 8 + bh) * 32768;
    float* C = o + ((size_t)b * LSEQ + seg * SEGL) * VDIM + h * DVV;

    __shared__ __align__(16) unsigned short As[128 * 32];
    __shared__ __align__(16) unsigned short Bs[128 * 32];
    const int t    = threadIdx.x;
    const int w    = t >> 6;
    const int lane = t & 63;
    const int m0 = blockIdx.x * 128;
    const int n0 = blockIdx.y * 128;
    const int mw = (w & 1) * 64;
    const int nw = (w >> 1) * 64;
    const int l15 = lane & 15;
    const int q4  = lane >> 4;

    f32x4 acc[4][4];
#pragma unroll
    for (int i = 0; i < 4; i++)
#pragma unroll
        for (int j = 0; j < 4; j++) {
            f32x4 zz = {0.f, 0.f, 0.f, 0.f};
            acc[i][j] = zz;
        }

    for (int k0 = 0; k0 < 128; k0 += 32) {
        __syncthreads();
#pragma unroll
        for (int jj = 0; jj < 2; jj++) {
            const int c   = w * 128 + jj * 64 + lane;
            const int row = c >> 2;
            const int col = (c & 3) * 8;
            __builtin_amdgcn_global_load_lds(
                (const __attribute__((address_space(1))) void*)(A + (size_t)(m0 + row) * KDIM + k0 + col),
                (__attribute__((address_space(3))) void*)((char*)As + (w * 128 + jj * 64) * 16),
                16, 0, 0);
            __builtin_amdgcn_global_load_lds(
                (const __attribute__((address_space(1))) void*)(B + (size_t)(n0 + row) * 128 + k0 + col),
                (__attribute__((address_space(3))) void*)((char*)Bs + (w * 128 + jj * 64) * 16),
                16, 0, 0);
        }
        __syncthreads();

        half8 a[4], bb[4];
#pragma unroll
        for (int i = 0; i < 4; i++)
            a[i] = *(const half8*)(As + (mw + i * 16 + l15) * 32 + q4 * 8);
#pragma unroll
        for (int j = 0; j < 4; j++)
            bb[j] = *(const half8*)(Bs + (nw + j * 16 + l15) * 32 + q4 * 8);
#pragma unroll
        for (int i = 0; i < 4; i++)
#pragma unroll
            for (int j = 0; j < 4; j++)
                acc[i][j] = __builtin_amdgcn_mfma_f32_16x16x32_f16(a[i], bb[j], acc[i][j], 0, 0, 0);
    }

#pragma unroll
    for (int i = 0; i < 4; i++) {
        const int m_base = m0 + mw + i * 16 + q4 * 4;
#pragma unroll
        for (int j = 0; j < 4; j++) {
            const int n = n0 + nw + j * 16 + l15;
#pragma unroll
            for (int rr = 0; rr < 4; rr++)
                C[(size_t)(m_base + rr) * VDIM + n] += acc[i][j][rr];
        }
    }
}

// ---------------------------------------------------------------------------
// prep: weight fp16 pack (Wr|Wk|Wv|Wg|Wo + padded Wx1/Ww1) fused with
// xl = x + (shift(x)-x)*mu_x -> fp16.  blocks 0..4479 = cvt, 4480.. = xl.
// ---------------------------------------------------------------------------
__global__ __launch_bounds__(256) void prep_kernel(
    const float* __restrict__ Wr, const float* __restrict__ Wk,
    const float* __restrict__ Wv, const float* __restrict__ Wg,
    const float* __restrict__ Wo, const float* __restrict__ Wx1,
    const float* __restrict__ Ww1,
    unsigned short* __restrict__ Wb, unsigned short* __restrict__ Wx1p,
    unsigned short* __restrict__ Ww1p,
    const float* __restrict__ x, const float* __restrict__ mux,
    unsigned short* __restrict__ xl16)
{
    const int bx = blockIdx.x;
    if (bx < 4480) {
        const int q = bx * 256 + threadIdx.x;   // quad index
        float4 v = make_float4(0.f, 0.f, 0.f, 0.f);
        unsigned short* dst;
        if (q < 1048576) {
            const int i4 = q * 4;
            const float* src; int off;
            if      (i4 <  524288) { src = Wr; off = i4; }
            else if (i4 < 1048576) { src = Wk; off = i4 -  524288; }
            else if (i4 < 2097152) { src = Wv; off = i4 - 1048576; }
            else if (i4 < 3145728) { src = Wg; off = i4 - 2097152; }
            else                   { src = Wo; off = i4 - 3145728; }
            v = *(const float4*)(src + off);
            dst = Wb + i4;
        } else if (q < 1114112) {
            const int e = (q - 1048576) * 4;
            const int row = e >> 10;
            if (row < 160) v = *(const float4*)(Wx1 + (size_t)row * H + (e & 1023));
            dst = Wx1p + e;
        } else {
            const int e = (q - 1114112) * 4;
            const int row = e >> 10;
            if (row < 64) v = *(const float4*)(Ww1 + (size_t)row * H + (e & 1023));
            dst = Ww1p + e;
        }
        ushort4 o4;
        o4.x = f2h(v.x); o4.y = f2h(v.y); o4.z = f2h(v.z); o4.w = f2h(v.w);
        *(ushort4*)dst = o4;
    } else {
        const int m = bx - 4480;
        const int c = threadIdx.x * 4;
        const float4 xv = *(const float4*)(x + (size_t)m * H + c);
        float4 pv = make_float4(0.f, 0.f, 0.f, 0.f);
        if ((m & (LSEQ - 1)) != 0)
            pv = *(const float4*)(x + (size_t)(m - 1) * H + c);
        const float4 mv = *(const float4*)(mux + c);
        ushort4 p;
        p.x = f2h(xv.x + (pv.x - xv.x) * mv.x);
        p.y = f2h(xv.y + (pv.y - xv.y) * mv.y);
        p.z = f2h(xv.z + (pv.z - xv.z) * mv.z);
        p.w = f2h(xv.w + (pv.w - xv.w) * mv.w);
        *(ushort4*)(xl16 + (size_t)m * H + c) = p;
    }
}

// ---------------------------------------------------------------------------
// Scan pass 1 v5: 4 v-columns per thread, XCD-grouped block swizzle.
// 512 blocks: blockIdx = seg*64 + vc*8 + bh  (same (seg,bh) -> same idx mod 8
// -> same XCD -> r/k/dec fetched once per XCD-local group).
// 256 threads = 32 kquad x 8 vl; thread owns k=kg*4..+3, v=vc*32+vl*4..+3.
// 16 S regs; r4+k4 via one pointer (+2KB imm), d4, v as float4; 1-step
// register prefetch (slack rows after buffers make the last prefetch safe).
// ---------------------------------------------------------------------------
__global__ __launch_bounds__(256, 2) void scan_pass1(
    const float* __restrict__ rk, const float* __restrict__ vg,
    const float* __restrict__ dec, const float* __restrict__ bonus,
    float* __restrict__ o, unsigned short* __restrict__ rt16,
    float* __restrict__ Sloc, float* __restrict__ Dtot)
{
    const int bh  = blockIdx.x & 7;
    const int vc  = (blockIdx.x >> 3) & 7;
    const int seg = blockIdx.x >> 6;
    const int b   = bh >> 2;
    const int h   = bh & 3;
    const int t   = threadIdx.x;
    const int kg  = t & 31;
    const int vl  = t >> 5;
    const bool wlead = (vc == 0) && (vl == 0);

    float S[4][4], D[4] = {1.f, 1.f, 1.f, 1.f}, u[4];
#pragma unroll
    for (int j = 0; j < 4; j++) {
        u[j] = bonus[h * DKK + kg * 4 + j];
#pragma unroll
        for (int jj = 0; jj < 4; jj++) S[j][jj] = 0.f;
    }

    const size_t row0 = (size_t)b * LSEQ + (size_t)seg * SEGL;
    const float* rp = rk  + row0 * 1024 + h * DKK + kg * 4;   // k at rp+512
    const float* dp = dec + row0 * 512  + h * DKK + kg * 4;
    const float* vp = vg  + row0 * 2048 + h * DVV + vc * 32 + vl * 4;
    float*       op = o   + row0 * 1024 + h * DVV + vc * 32 + vl * 4;
    unsigned short* rt = rt16 + row0 * 512 + h * DKK + kg * 4;

    float4 cr = *(const float4*)rp;
    float4 ck = *(const float4*)(rp + 512);
    float4 cd = *(const float4*)dp;
    float4 cv = *(const float4*)vp;
    rp += 1024; dp += 512; vp += 2048;

    for (int t0 = 0; t0 < SEGL; ++t0) {
        const float4 nr = *(const float4*)rp;          // last iter reads slack row
        const float4 nk = *(const float4*)(rp + 512);
        const float4 nd = *(const float4*)dp;
        const float4 nv = *(const float4*)vp;
        rp += 1024; dp += 512; vp += 2048;

        if (wlead) {   // r~ = r * D (exclusive cumprod), fp16
            ushort4 p;
            p.x = f2h(cr.x * D[0]); p.y = f2h(cr.y * D[1]);
            p.z = f2h(cr.z * D[2]); p.w = f2h(cr.w * D[3]);
            *(ushort4*)rt = p;
        }
        rt += 512;

        const float ra[4] = {cr.x, cr.y, cr.z, cr.w};
        const float ka[4] = {ck.x, ck.y, ck.z, ck.w};
        const float da[4] = {cd.x, cd.y, cd.z, cd.w};
        const float va[4] = {cv.x, cv.y, cv.z, cv.w};
        float part[4] = {0.f, 0.f, 0.f, 0.f};
#pragma unroll
        for (int j = 0; j < 4; j++) {
#pragma unroll
            for (int jj = 0; jj < 4; jj++) {
                const float kv = ka[j] * va[jj];
                part[jj] = fmaf(ra[j], fmaf(u[j], kv, S[j][jj]), part[jj]);
                S[j][jj] = fmaf(da[j], S[j][jj], kv);
            }
            D[j] *= da[j];
        }
#pragma unroll
        for (int jj = 0; jj < 4; jj++) {
            part[jj] = dpp_add<0xB1>(part[jj]);    // quad_perm xor1
            part[jj] = dpp_add<0x4E>(part[jj]);    // quad_perm xor2
            part[jj] = dpp_add<0x141>(part[jj]);   // row_half_mirror
            part[jj] = dpp_add<0x140>(part[jj]);   // row_mirror
            part[jj] = dpp_add<0x142>(part[jj]);   // row_bcast15
        }
        if (kg == 31) {
            float4 res = make_float4(part[0], part[1], part[2], part[3]);
            *(float4*)op = res;
        }
        op += 1024;
        cr = nr; ck = nk; cd = nd; cv = nv;
    }

    {   // segment-final state [k][vcol] + total decay
        float* sl = Sloc + (size_t)(seg * 8 + bh) * 32768
                    + (size_t)(kg * 4) * 256 + vc * 32 + vl * 4;
#pragma unroll
        for (int j = 0; j < 4; j++) {
            float4 sv = make_float4(S[j][0], S[j][1], S[j][2], S[j][3]);
            *(float4*)(sl + j * 256) = sv;
        }
        if (wlead) {
            float* dt = Dtot + (seg * 8 + bh) * 128 + kg * 4;
#pragma unroll
            for (int j = 0; j < 4; j++) dt[j] = D[j];
        }
    }
}

// ---------------------------------------------------------------------------
// Scan pass 2: propagate entry states across segments; Sentry^T as fp16.
// ---------------------------------------------------------------------------
__global__ __launch_bounds__(256) void scan_pass2(
    const float* __restrict__ Sloc, const float* __restrict__ Dtot,
    unsigned short* __restrict__ SentryT16)
{
    const int vc = blockIdx.x & 31;
    const int bh = blockIdx.x >> 5;
    const int t  = threadIdx.x;
    const int kg = t & 31;
    const int vl = t >> 5;

    float S[4] = {0.f, 0.f, 0.f, 0.f};
    for (int p = 0; p < NSEG; p++) {
        unsigned short* st = SentryT16 + (size_t)(p * 8 + bh) * 32768
                             + (size_t)(vc * 8 + vl) * 128 + kg * 4;
        ushort4 pk;
        pk.x = f2h(S[0]); pk.y = f2h(S[1]); pk.z = f2h(S[2]); pk.w = f2h(S[3]);
        *(ushort4*)st = pk;
        if (p < NSEG - 1) {
            const float* sl = Sloc + (size_t)(p * 8 + bh) * 32768
                              + (size_t)(kg * 4) * 256 + vc * 8 + vl;
            const float* dt = Dtot + (p * 8 + bh) * 128 + kg * 4;
#pragma unroll
            for (int j = 0; j < 4; j++) S[j] = dt[j] * S[j] + sl[j * 256];
        }
    }
}

// ---------------------------------------------------------------------------
// Per-head LayerNorm + swish gate -> fp16. g lives in the fused vg buffer.
// ---------------------------------------------------------------------------
__global__ __launch_bounds__(256) void ln_gate_kernel(
    const float* __restrict__ o, const float* __restrict__ vg,
    const float* __restrict__ lnw, const float* __restrict__ lnb,
    unsigned short* __restrict__ out)
{
    const int m    = blockIdx.x;
    const int t    = threadIdx.x;
    const int h    = t >> 6;
    const int lane = t & 63;
    const size_t obase = (size_t)m * VDIM + (size_t)h * DVV + lane * 4;
    const size_t gbase = (size_t)m * 2048 + 1024 + (size_t)h * DVV + lane * 4;
    const float4 ov = *(const float4*)(o + obase);
    float sum = ov.x + ov.y + ov.z + ov.w;
    float sq  = ov.x * ov.x + ov.y * ov.y + ov.z * ov.z + ov.w * ov.w;
#pragma unroll
    for (int off = 1; off < 64; off <<= 1) {
        sum += __shfl_xor(sum, off);
        sq  += __shfl_xor(sq, off);
    }
    const float mean = sum * (1.f / DVV);
    const float var  = sq * (1.f / DVV) - mean * mean;
    const float rstd = rsqrtf(var + 1e-5f);
    const float4 gv = *(const float4*)(vg + gbase);
    const float4 wv = *(const float4*)(lnw + lane * 4);
    const float4 bv = *(const float4*)(lnb + lane * 4);
    float4 res;
    res.x = ((ov.x - mean) * rstd * wv.x + bv.x) * (gv.x / (1.f + expf(-gv.x)));
    res.y = ((ov.y - mean) * rstd * wv.y + bv.y) * (gv.y / (1.f + expf(-gv.y)));
    res.z = ((ov.z - mean) * rstd * wv.z + bv.z) * (gv.z / (1.f + expf(-gv.z)));
    res.w = ((ov.w - mean) * rstd * wv.w + bv.w) * (gv.w / (1.f + expf(-gv.w)));
    ushort4 p;
    p.x = f2h(res.x); p.y = f2h(res.y); p.z = f2h(res.z); p.w = f2h(res.w);
    *(ushort4*)(out + obase) = p;
}

extern "C" void kernel_launch(void* const* d_in, const int* in_sizes, int n_in,
                              void* d_out, int out_size, void* d_ws, size_t ws_size,
                              hipStream_t stream)
{
    const float* x     = (const float*)d_in[0];
    const float* mu_x  = (const float*)d_in[1];
    const float* Wx1   = (const float*)d_in[2];
    const float* Wx2   = (const float*)d_in[3];
    const float* xb    = (const float*)d_in[4];
    const float* Wr    = (const float*)d_in[5];
    const float* Wk    = (const float*)d_in[6];
    const float* Wv    = (const float*)d_in[7];
    const float* Wg    = (const float*)d_in[8];
    const float* Ww1   = (const float*)d_in[9];
    const float* Ww2   = (const float*)d_in[10];
    const float* bw2   = (const float*)d_in[11];
    const float* bonus = (const float*)d_in[12];
    const float* lnw   = (const float*)d_in[13];
    const float* lnb   = (const float*)d_in[14];
    const float* Wo    = (const float*)d_in[15];
    float* out = (float*)d_out;
    (void)in_sizes; (void)n_in; (void)out_size; (void)ws_size;

    float* ws = (float*)d_ws;
    // layout (f32 word offsets) — slack rows after rkB/vgB/decB for the
    // scan's unconditional 1-step prefetch.
    unsigned short* Wx1p = (unsigned short*)(ws + 0);         // 256x1024 fp16
    unsigned short* Ww1p = (unsigned short*)(ws + 131072);    // 128x1024 fp16
    unsigned short* Wb   = (unsigned short*)(ws + 196608);    // 5 packed weights fp16
    float* xp    = ws + 2293760;                              // 4096x256 f32
    float* insB  = ws + 3342336;                              // 5 fp16 slots x 2097152 words
    float* rkB   = ws + 13828096;                             // 4096x1024 f32 (+1024 slack)
    float* vgB   = ws + 18023424;                             // 4096x2048 f32 (+2048 slack)
    float* wlow  = ws + 26414080;                             // 4096x128 f32
    float* decB  = ws + 26938368;                             // 4096x512 f32 (+512 slack)

    unsigned short* insb = (unsigned short*)insB;             // slot n: insb + n*4194304
    unsigned short* Wrb  = Wb;                                // rows 0-1023 = [Wr;Wk]
    unsigned short* Wvb  = Wb + 1048576;                      // rows 0-2047 = [Wv;Wg]
    unsigned short* Wob  = Wb + 3145728;
    unsigned short* xl16 = (unsigned short*)rkB;              // dead before rk GEMM writes
    // scan-time aliases over consumed fp16 slots
    float*          o       = insB;                                   // slots 0,1
    unsigned short* rt16    = insb + 2ul * 4194304;                   // slot 2
    float*          Sloc    = insB + 3ul * 2097152;                   // slot 3
    unsigned short* gatedb  = (unsigned short*)(insB + 3ul * 2097152);// slot 3 (after Sloc dead)
    float*          Dtot    = insB + 4ul * 2097152;                   // slot 4
    unsigned short* SentryT16 = (unsigned short*)(Dtot + 8192);       // slot 4

    dim3 blk(256);

    prep_kernel<<<dim3(8576), blk, 0, stream>>>(Wr, Wk, Wv, Wg, Wo, Wx1, Ww1,
                                                Wb, Wx1p, Ww1p, x, mu_x, xl16);

    // xp = tanh(xl @ Wx1p^T)  [4096 x 256 f32, cols 160.. are zero]
    gemm_mfma_bt<EPI_TANH><<<dim3(32, 2), blk, 0, stream>>>(
        xl16, xl16, 1 << 30, H, Wx1p, H, xp, 256, H);

    // fused thin-K: in_n = x + delta*(xp_n @ Wx2_n^T + x_bias_n) -> fp16 slot n
    gemm_bt<EPI_LERP><<<dim3(64, 16, 5), blk, 0, stream>>>(
        xp, 256, 0, Wx2, 160, 0, nullptr, insb, H, MTOT, H, 32, x, xb);

    // wlow = tanh(in_w16 @ Ww1p^T)  [4096 x 128 f32, cols 64.. zero]
    gemm_mfma_bt<EPI_TANH><<<dim3(32, 1), blk, 0, stream>>>(
        insb + 1ul * 4194304, insb + 1ul * 4194304, 1 << 30, H, Ww1p, H, wlow, 128, H);

    // dec = exp(-exp(wlow @ Ww2^T + bw2))  (f32 VALU, K=64)
    gemm_bt<EPI_DEC><<<dim3(64, 8), blk, 0, stream>>>(
        wlow, 128, 0, Ww2, GRR, 0, decB, nullptr, KDIM, MTOT, KDIM, GRR, nullptr, bw2);

    // fused projections: rk = [r|k] (N=1024), vg = [v|g] (N=2048)
    gemm_mfma_bt<EPI_NONE><<<dim3(32, 8), blk, 0, stream>>>(
        insb + 0ul * 4194304, insb + 2ul * 4194304, 512, H, Wrb, H, rkB, 1024, H);
    gemm_mfma_bt<EPI_NONE><<<dim3(32, 16), blk, 0, stream>>>(
        insb + 3ul * 4194304, insb + 4ul * 4194304, 1024, H, Wvb, H, vgB, 2048, H);

    // segmented RWKV scan (XCD-swizzled)
    scan_pass1<<<dim3(512), blk, 0, stream>>>(rkB, vgB, decB, bonus, o, rt16, Sloc, Dtot);
    scan_pass2<<<dim3(256), blk, 0, stream>>>(Sloc, Dtot, SentryT16);
    gemm_mfma_corr<<<dim3(2, 2, 56), blk, 0, stream>>>(rt16, SentryT16, o);

    // per-head LN + swish gate -> fp16 gated
    ln_gate_kernel<<<dim3(4096), blk, 0, stream>>>(o, vgB, lnw, lnb, gatedb);

    // out = gated @ Wo^T
    gemm_mfma_bt<EPI_NONE><<<dim3(32, 8), blk, 0, stream>>>(
        gatedb, gatedb, 1 << 30, VDIM, Wob, VDIM, out, H, VDIM);
}

// Round 9
// 424.853 us; speedup vs baseline: 4.2306x; 1.1475x over previous
//
#include <hip/hip_runtime.h>
#include <cstdint>
#include <cstddef>

#define H     1024
#define LSEQ  2048
#define NHH   4
#define DKK   128
#define DVV   256
#define KDIM  512
#define VDIM  1024
#define GRR   64
#define MTOT  4096   // B*L
#define SEGL  128    // scan segment length
#define NSEG  16

enum { EPI_NONE = 0, EPI_TANH = 1, EPI_LERP = 2, EPI_DEC = 3, EPI_TANH16 = 4 };

typedef __attribute__((ext_vector_type(8))) _Float16 half8;
typedef __attribute__((ext_vector_type(4))) float f32x4;
typedef __attribute__((ext_vector_type(2))) float f32x2;

static __device__ __forceinline__ unsigned short f2h(float f) {
    _Float16 h = (_Float16)f;          // v_cvt_f16_f32, RNE
    union { _Float16 h; unsigned short u; } c;
    c.h = h;
    return c.u;
}

// DPP-based partial-wave reduction step: return x + dpp_move(x, CTRL). Pure VALU.
template<int CTRL>
static __device__ __forceinline__ float dpp_add(float x) {
    int xi = __float_as_int(x);
    int mv = __builtin_amdgcn_update_dpp(0, xi, CTRL, 0xf, 0xf, true);
    return x + __int_as_float(mv);
}

// ---------------------------------------------------------------------------
// f32 VALU GEMM: C[m][n] = sum_k A[m][k+acol]*B[n][k+bcol]
// EPI_LERP instantiation is the fused 5-way thin-K kernel: blockIdx.z picks
// the mixing branch (acol/bcol += z*32, bias += z*H, C2 += z*slot).
// ---------------------------------------------------------------------------
template<int EPI>
__global__ __launch_bounds__(256) void gemm_bt(
    const float* __restrict__ A, int lda, int acol,
    const float* __restrict__ B, int ldb, int bcol,
    float* __restrict__ Cf, unsigned short* __restrict__ C2, int ldc,
    int M, int N, int K,
    const float* __restrict__ xsrc,   // LERP epilogue source (ld = H)
    const float* __restrict__ bias)   // LERP: x_bias row
{
    if constexpr (EPI == EPI_LERP) {
        const int zz = blockIdx.z;
        acol += zz * 32;
        bcol += zz * 32;
        bias += zz * H;
        C2   += (size_t)zz * 4194304;   // fp16 slot stride
    }
    __shared__ float As[16][64];
    __shared__ float Bs[16][64];
    const int m0 = blockIdx.x * 64;
    const int n0 = blockIdx.y * 64;
    const int t  = threadIdx.x;
    const int tx = t & 15, ty = t >> 4;
    const int sm = t >> 2;          // staging row 0..63
    const int sq = (t & 3) * 4;     // staging k-quad

    float acc[4][4];
#pragma unroll
    for (int i = 0; i < 4; i++)
#pragma unroll
        for (int j = 0; j < 4; j++) acc[i][j] = 0.f;

    for (int k0 = 0; k0 < K; k0 += 16) {
        {   // stage A (M multiple of 64)
            const int m = m0 + sm;
            const float4 av = *(const float4*)(A + (size_t)m * lda + acol + k0 + sq);
            As[sq + 0][sm] = av.x; As[sq + 1][sm] = av.y;
            As[sq + 2][sm] = av.z; As[sq + 3][sm] = av.w;
        }
        {   // stage B
            const int n = n0 + sm;
            float4 bv = make_float4(0.f, 0.f, 0.f, 0.f);
            if (n < N) bv = *(const float4*)(B + (size_t)n * ldb + bcol + k0 + sq);
            Bs[sq + 0][sm] = bv.x; Bs[sq + 1][sm] = bv.y;
            Bs[sq + 2][sm] = bv.z; Bs[sq + 3][sm] = bv.w;
        }
        __syncthreads();
#pragma unroll
        for (int kk = 0; kk < 16; kk++) {
            const float4 a = *(const float4*)&As[kk][ty * 4];
            const float4 b = *(const float4*)&Bs[kk][tx * 4];
            const float av2[4] = {a.x, a.y, a.z, a.w};
            const float bv2[4] = {b.x, b.y, b.z, b.w};
#pragma unroll
            for (int i = 0; i < 4; i++)
#pragma unroll
                for (int j = 0; j < 4; j++) acc[i][j] += av2[i] * bv2[j];
        }
        __syncthreads();
    }

    const int nbase = n0 + tx * 4;
    if (nbase >= N) return;
#pragma unroll
    for (int i = 0; i < 4; i++) {
        const int m = m0 + ty * 4 + i;
        float4 r = make_float4(acc[i][0], acc[i][1], acc[i][2], acc[i][3]);
        if constexpr (EPI == EPI_LERP) {
            const float4 bb = *(const float4*)(bias + nbase);
            const float4 xv = *(const float4*)(xsrc + (size_t)m * H + nbase);
            float4 pv = make_float4(0.f, 0.f, 0.f, 0.f);
            if ((m & (LSEQ - 1)) != 0)
                pv = *(const float4*)(xsrc + (size_t)(m - 1) * H + nbase);
            r.x = xv.x + (pv.x - xv.x) * (r.x + bb.x);
            r.y = xv.y + (pv.y - xv.y) * (r.y + bb.y);
            r.z = xv.z + (pv.z - xv.z) * (r.z + bb.z);
            r.w = xv.w + (pv.w - xv.w) * (r.w + bb.w);
        }
        if (Cf) *(float4*)(Cf + (size_t)m * ldc + nbase) = r;
        if (C2) {
            ushort4 p;
            p.x = f2h(r.x); p.y = f2h(r.y); p.z = f2h(r.z); p.w = f2h(r.w);
            *(ushort4*)(C2 + (size_t)m * ldc + nbase) = p;
        }
    }
}

// ---------------------------------------------------------------------------
// fp16 MFMA GEMM (m97 structure): C[m][n] = sum_k A[m][k] * B[n][k].
// A2/nsplit: blocks with n0 >= nsplit read A2 (fused r|k and v|g launches).
// EPI_TANH: f32 tanh out.  EPI_TANH16: fp16 tanh out (Ch).
// EPI_DEC: f32 exp(-exp(val+bias[n])) out.
// ---------------------------------------------------------------------------
template<int EPI>
__global__ __launch_bounds__(256) void gemm_mfma_bt(
    const unsigned short* __restrict__ A,
    const unsigned short* __restrict__ A2, int nsplit, int lda,
    const unsigned short* __restrict__ B, int ldb,
    float* __restrict__ C, unsigned short* __restrict__ Ch, int ldc, int K,
    const float* __restrict__ bias)
{
    __shared__ __align__(16) unsigned short As[128 * 32];
    __shared__ __align__(16) unsigned short Bs[128 * 32];
    const int t    = threadIdx.x;
    const int w    = t >> 6;
    const int lane = t & 63;
    const int m0 = blockIdx.x * 128;
    const int n0 = blockIdx.y * 128;
    const unsigned short* Au = (n0 < nsplit) ? A : A2;
    const int mw = (w & 1) * 64;
    const int nw = (w >> 1) * 64;
    const int l15 = lane & 15;
    const int q4  = lane >> 4;

    f32x4 acc[4][4];
#pragma unroll
    for (int i = 0; i < 4; i++)
#pragma unroll
        for (int j = 0; j < 4; j++) {
            f32x4 z = {0.f, 0.f, 0.f, 0.f};
            acc[i][j] = z;
        }

    for (int k0 = 0; k0 < K; k0 += 32) {
        __syncthreads();
#pragma unroll
        for (int jj = 0; jj < 2; jj++) {
            const int c   = w * 128 + jj * 64 + lane;   // 16B chunk id
            const int row = c >> 2;
            const int col = (c & 3) * 8;
            __builtin_amdgcn_global_load_lds(
                (const __attribute__((address_space(1))) void*)(Au + (size_t)(m0 + row) * lda + k0 + col),
                (__attribute__((address_space(3))) void*)((char*)As + (w * 128 + jj * 64) * 16),
                16, 0, 0);
            __builtin_amdgcn_global_load_lds(
                (const __attribute__((address_space(1))) void*)(B + (size_t)(n0 + row) * ldb + k0 + col),
                (__attribute__((address_space(3))) void*)((char*)Bs + (w * 128 + jj * 64) * 16),
                16, 0, 0);
        }
        __syncthreads();

        half8 a[4], b[4];
#pragma unroll
        for (int i = 0; i < 4; i++)
            a[i] = *(const half8*)(As + (mw + i * 16 + l15) * 32 + q4 * 8);
#pragma unroll
        for (int j = 0; j < 4; j++)
            b[j] = *(const half8*)(Bs + (nw + j * 16 + l15) * 32 + q4 * 8);
#pragma unroll
        for (int i = 0; i < 4; i++)
#pragma unroll
            for (int j = 0; j < 4; j++)
                acc[i][j] = __builtin_amdgcn_mfma_f32_16x16x32_f16(a[i], b[j], acc[i][j], 0, 0, 0);
    }

#pragma unroll
    for (int i = 0; i < 4; i++) {
        const int m_base = m0 + mw + i * 16 + q4 * 4;
#pragma unroll
        for (int j = 0; j < 4; j++) {
            const int n = n0 + nw + j * 16 + l15;
#pragma unroll
            for (int r = 0; r < 4; r++) {
                float val = acc[i][j][r];
                if constexpr (EPI == EPI_TANH) {
                    C[(size_t)(m_base + r) * ldc + n] = tanhf(val);
                } else if constexpr (EPI == EPI_TANH16) {
                    Ch[(size_t)(m_base + r) * ldc + n] = f2h(tanhf(val));
                } else if constexpr (EPI == EPI_DEC) {
                    C[(size_t)(m_base + r) * ldc + n] = expf(-expf(val + bias[n]));
                } else {
                    C[(size_t)(m_base + r) * ldc + n] = val;
                }
            }
        }
    }
}

// ---------------------------------------------------------------------------
// Batched fp16 MFMA GEMM with C-accumulate (scan correction):
// o[seg,bh][m,n] += sum_k rt16[m,k] * SentryT16[n,k].  M=128, N=256, K=128.
// grid (1, 2, 120): z = (seg-1)*8 + bh.
// ---------------------------------------------------------------------------
__global__ __launch_bounds__(256) void gemm_mfma_corr(
    const unsigned short* __restrict__ rt16,
    const unsigned short* __restrict__ SentryT16,
    float* __restrict__ o)
{
    const int z   = blockIdx.z;
    const int seg = (z >> 3) + 1;
    const int bh  = z & 7;
    const int b   = bh >> 2, h = bh & 3;
    const unsigned short* A = rt16 + ((size_t)b * LSEQ + seg * SEGL) * KDIM + h * DKK;
    const unsigned short* B = SentryT16 + (size_t)(seg * 8 + bh) * 32768;
    float* C = o + ((size_t)b * LSEQ + seg * SEGL) * VDIM + h * DVV;

    __shared__ __align__(16) unsigned short As[128 * 32];
    __shared__ __align__(16) unsigned short Bs[128 * 32];
    const int t    = threadIdx.x;
    const int w    = t >> 6;
    const int lane = t & 63;
    const int m0 = blockIdx.x * 128;
    const int n0 = blockIdx.y * 128;
    const int mw = (w & 1) * 64;
    const int nw = (w >> 1) * 64;
    const int l15 = lane & 15;
    const int q4  = lane >> 4;

    f32x4 acc[4][4];
#pragma unroll
    for (int i = 0; i < 4; i++)
#pragma unroll
        for (int j = 0; j < 4; j++) {
            f32x4 zz = {0.f, 0.f, 0.f, 0.f};
            acc[i][j] = zz;
        }

    for (int k0 = 0; k0 < 128; k0 += 32) {
        __syncthreads();
#pragma unroll
        for (int jj = 0; jj < 2; jj++) {
            const int c   = w * 128 + jj * 64 + lane;
            const int row = c >> 2;
            const int col = (c & 3) * 8;
            __builtin_amdgcn_global_load_lds(
                (const __attribute__((address_space(1))) void*)(A + (size_t)(m0 + row) * KDIM + k0 + col),
                (__attribute__((address_space(3))) void*)((char*)As + (w * 128 + jj * 64) * 16),
                16, 0, 0);
            __builtin_amdgcn_global_load_lds(
                (const __attribute__((address_space(1))) void*)(B + (size_t)(n0 + row) * 128 + k0 + col),
                (__attribute__((address_space(3))) void*)((char*)Bs + (w * 128 + jj * 64) * 16),
                16, 0, 0);
        }
        __syncthreads();

        half8 a[4], bb[4];
#pragma unroll
        for (int i = 0; i < 4; i++)
            a[i] = *(const half8*)(As + (mw + i * 16 + l15) * 32 + q4 * 8);
#pragma unroll
        for (int j = 0; j < 4; j++)
            bb[j] = *(const half8*)(Bs + (nw + j * 16 + l15) * 32 + q4 * 8);
#pragma unroll
        for (int i = 0; i < 4; i++)
#pragma unroll
            for (int j = 0; j < 4; j++)
                acc[i][j] = __builtin_amdgcn_mfma_f32_16x16x32_f16(a[i], bb[j], acc[i][j], 0, 0, 0);
    }

#pragma unroll
    for (int i = 0; i < 4; i++) {
        const int m_base = m0 + mw + i * 16 + q4 * 4;
#pragma unroll
        for (int j = 0; j < 4; j++) {
            const int n = n0 + nw + j * 16 + l15;
#pragma unroll
            for (int rr = 0; rr < 4; rr++)
                C[(size_t)(m_base + rr) * VDIM + n] += acc[i][j][rr];
        }
    }
}

// ---------------------------------------------------------------------------
// prep: fp16 packs (Wr|Wk|Wv|Wg|Wo, padded Wx1/Ww1, Ww2) fused with
// xl = x + (shift(x)-x)*mu_x -> fp16.  blocks 0..4511 = cvt, 4512.. = xl.
// ---------------------------------------------------------------------------
__global__ __launch_bounds__(256) void prep_kernel(
    const float* __restrict__ Wr, const float* __restrict__ Wk,
    const float* __restrict__ Wv, const float* __restrict__ Wg,
    const float* __restrict__ Wo, const float* __restrict__ Wx1,
    const float* __restrict__ Ww1, const float* __restrict__ Ww2,
    unsigned short* __restrict__ Wb, unsigned short* __restrict__ Wx1p,
    unsigned short* __restrict__ Ww1p, unsigned short* __restrict__ Ww2p,
    const float* __restrict__ x, const float* __restrict__ mux,
    unsigned short* __restrict__ xl16)
{
    const int bx = blockIdx.x;
    if (bx < 4512) {
        const int q = bx * 256 + threadIdx.x;   // quad index
        float4 v = make_float4(0.f, 0.f, 0.f, 0.f);
        unsigned short* dst;
        if (q < 1048576) {
            const int i4 = q * 4;
            const float* src; int off;
            if      (i4 <  524288) { src = Wr; off = i4; }
            else if (i4 < 1048576) { src = Wk; off = i4 -  524288; }
            else if (i4 < 2097152) { src = Wv; off = i4 - 1048576; }
            else if (i4 < 3145728) { src = Wg; off = i4 - 2097152; }
            else                   { src = Wo; off = i4 - 3145728; }
            v = *(const float4*)(src + off);
            dst = Wb + i4;
        } else if (q < 1114112) {
            const int e = (q - 1048576) * 4;
            const int row = e >> 10;
            if (row < 160) v = *(const float4*)(Wx1 + (size_t)row * H + (e & 1023));
            dst = Wx1p + e;
        } else if (q < 1146880) {
            const int e = (q - 1114112) * 4;
            const int row = e >> 10;
            if (row < 64) v = *(const float4*)(Ww1 + (size_t)row * H + (e & 1023));
            dst = Ww1p + e;
        } else {
            const int e = (q - 1146880) * 4;       // 32768 contiguous elems
            v = *(const float4*)(Ww2 + e);
            dst = Ww2p + e;
        }
        ushort4 o4;
        o4.x = f2h(v.x); o4.y = f2h(v.y); o4.z = f2h(v.z); o4.w = f2h(v.w);
        *(ushort4*)dst = o4;
    } else {
        const int m = bx - 4512;
        const int c = threadIdx.x * 4;
        const float4 xv = *(const float4*)(x + (size_t)m * H + c);
        float4 pv = make_float4(0.f, 0.f, 0.f, 0.f);
        if ((m & (LSEQ - 1)) != 0)
            pv = *(const float4*)(x + (size_t)(m - 1) * H + c);
        const float4 mv = *(const float4*)(mux + c);
        ushort4 p;
        p.x = f2h(xv.x + (pv.x - xv.x) * mv.x);
        p.y = f2h(xv.y + (pv.y - xv.y) * mv.y);
        p.z = f2h(xv.z + (pv.z - xv.z) * mv.z);
        p.w = f2h(xv.w + (pv.w - xv.w) * mv.w);
        *(ushort4*)(xl16 + (size_t)m * H + c) = p;
    }
}

// ---------------------------------------------------------------------------
// Scan pass 1 v6: 16 segments (TLP: 1024 blocks = 4 waves/SIMD), 4 v-cols per
// thread, packed-f32 math (v_pk_fma_f32), XCD-grouped swizzle, DPP reduce.
// blockIdx = seg*64 + vc*8 + bh.
// ---------------------------------------------------------------------------
__global__ __launch_bounds__(256, 4) void scan_pass1(
    const float* __restrict__ rk, const float* __restrict__ vg,
    const float* __restrict__ dec, const float* __restrict__ bonus,
    float* __restrict__ o, unsigned short* __restrict__ rt16,
    float* __restrict__ Sloc, float* __restrict__ Dtot)
{
    const int bh  = blockIdx.x & 7;
    const int vc  = (blockIdx.x >> 3) & 7;
    const int seg = blockIdx.x >> 6;           // 0..15
    const int b   = bh >> 2;
    const int h   = bh & 3;
    const int t   = threadIdx.x;
    const int kg  = t & 31;
    const int vl  = t >> 5;
    const bool wlead = (vc == 0) && (vl == 0);

    f32x2 S2[4][2];
    float D[4] = {1.f, 1.f, 1.f, 1.f}, u[4];
#pragma unroll
    for (int j = 0; j < 4; j++) {
        u[j] = bonus[h * DKK + kg * 4 + j];
        f32x2 z = {0.f, 0.f};
        S2[j][0] = z; S2[j][1] = z;
    }

    const size_t row0 = (size_t)b * LSEQ + (size_t)seg * SEGL;
    const float* rp = rk  + row0 * 1024 + h * DKK + kg * 4;   // k at rp+512
    const float* dp = dec + row0 * 512  + h * DKK + kg * 4;
    const float* vp = vg  + row0 * 2048 + h * DVV + vc * 32 + vl * 4;
    float*       op = o   + row0 * 1024 + h * DVV + vc * 32 + vl * 4;
    unsigned short* rt = rt16 + row0 * 512 + h * DKK + kg * 4;

    float4 cr = *(const float4*)rp;
    float4 ck = *(const float4*)(rp + 512);
    float4 cd = *(const float4*)dp;
    float4 cv = *(const float4*)vp;
    rp += 1024; dp += 512; vp += 2048;

    for (int t0 = 0; t0 < SEGL; ++t0) {
        const float4 nr = *(const float4*)rp;          // last iter reads slack row
        const float4 nk = *(const float4*)(rp + 512);
        const float4 nd = *(const float4*)dp;
        const float4 nv = *(const float4*)vp;
        rp += 1024; dp += 512; vp += 2048;

        if (wlead) {   // r~ = r * D (exclusive cumprod), fp16
            ushort4 p;
            p.x = f2h(cr.x * D[0]); p.y = f2h(cr.y * D[1]);
            p.z = f2h(cr.z * D[2]); p.w = f2h(cr.w * D[3]);
            *(ushort4*)rt = p;
        }
        rt += 512;

        const float ra[4] = {cr.x, cr.y, cr.z, cr.w};
        const float ka[4] = {ck.x, ck.y, ck.z, ck.w};
        const float da[4] = {cd.x, cd.y, cd.z, cd.w};
        f32x2 va2[2];
        va2[0].x = cv.x; va2[0].y = cv.y;
        va2[1].x = cv.z; va2[1].y = cv.w;
        f32x2 part2[2];
        part2[0] = (f32x2){0.f, 0.f};
        part2[1] = (f32x2){0.f, 0.f};
#pragma unroll
        for (int j = 0; j < 4; j++) {
#pragma unroll
            for (int p = 0; p < 2; p++) {
                const f32x2 kv2 = va2[p] * ka[j];
                part2[p] += ra[j] * (S2[j][p] + u[j] * kv2);
                S2[j][p] = da[j] * S2[j][p] + kv2;
            }
            D[j] *= da[j];
        }
        float part[4] = {part2[0].x, part2[0].y, part2[1].x, part2[1].y};
#pragma unroll
        for (int jj = 0; jj < 4; jj++) {
            part[jj] = dpp_add<0xB1>(part[jj]);    // quad_perm xor1
            part[jj] = dpp_add<0x4E>(part[jj]);    // quad_perm xor2
            part[jj] = dpp_add<0x141>(part[jj]);   // row_half_mirror
            part[jj] = dpp_add<0x140>(part[jj]);   // row_mirror
            part[jj] = dpp_add<0x142>(part[jj]);   // row_bcast15
        }
        if (kg == 31) {
            float4 res = make_float4(part[0], part[1], part[2], part[3]);
            *(float4*)op = res;
        }
        op += 1024;
        cr = nr; ck = nk; cd = nd; cv = nv;
    }

    {   // segment-final state [k][vcol] + total decay
        float* sl = Sloc + (size_t)(seg * 8 + bh) * 32768
                    + (size_t)(kg * 4) * 256 + vc * 32 + vl * 4;
#pragma unroll
        for (int j = 0; j < 4; j++) {
            float4 sv = make_float4(S2[j][0].x, S2[j][0].y, S2[j][1].x, S2[j][1].y);
            *(float4*)(sl + j * 256) = sv;
        }
        if (wlead) {
            float* dt = Dtot + (seg * 8 + bh) * 128 + kg * 4;
#pragma unroll
            for (int j = 0; j < 4; j++) dt[j] = D[j];
        }
    }
}

// ---------------------------------------------------------------------------
// Scan pass 2: propagate entry states across 16 segments; Sentry^T as fp16.
// ---------------------------------------------------------------------------
__global__ __launch_bounds__(256) void scan_pass2(
    const float* __restrict__ Sloc, const float* __restrict__ Dtot,
    unsigned short* __restrict__ SentryT16)
{
    const int vc = blockIdx.x & 31;
    const int bh = blockIdx.x >> 5;
    const int t  = threadIdx.x;
    const int kg = t & 31;
    const int vl = t >> 5;

    float S[4] = {0.f, 0.f, 0.f, 0.f};
    for (int p = 0; p < NSEG; p++) {
        unsigned short* st = SentryT16 + (size_t)(p * 8 + bh) * 32768
                             + (size_t)(vc * 8 + vl) * 128 + kg * 4;
        ushort4 pk;
        pk.x = f2h(S[0]); pk.y = f2h(S[1]); pk.z = f2h(S[2]); pk.w = f2h(S[3]);
        *(ushort4*)st = pk;
        if (p < NSEG - 1) {
            const float* sl = Sloc + (size_t)(p * 8 + bh) * 32768
                              + (size_t)(kg * 4) * 256 + vc * 8 + vl;
            const float* dt = Dtot + (p * 8 + bh) * 128 + kg * 4;
#pragma unroll
            for (int j = 0; j < 4; j++) S[j] = dt[j] * S[j] + sl[j * 256];
        }
    }
}

// ---------------------------------------------------------------------------
// Per-head LayerNorm + swish gate -> fp16. g lives in the fused vg buffer.
// ---------------------------------------------------------------------------
__global__ __launch_bounds__(256) void ln_gate_kernel(
    const float* __restrict__ o, const float* __restrict__ vg,
    const float* __restrict__ lnw, const float* __restrict__ lnb,
    unsigned short* __restrict__ out)
{
    const int m    = blockIdx.x;
    const int t    = threadIdx.x;
    const int h    = t >> 6;
    const int lane = t & 63;
    const size_t obase = (size_t)m * VDIM + (size_t)h * DVV + lane * 4;
    const size_t gbase = (size_t)m * 2048 + 1024 + (size_t)h * DVV + lane * 4;
    const float4 ov = *(const float4*)(o + obase);
    float sum = ov.x + ov.y + ov.z + ov.w;
    float sq  = ov.x * ov.x + ov.y * ov.y + ov.z * ov.z + ov.w * ov.w;
#pragma unroll
    for (int off = 1; off < 64; off <<= 1) {
        sum += __shfl_xor(sum, off);
        sq  += __shfl_xor(sq, off);
    }
    const float mean = sum * (1.f / DVV);
    const float var  = sq * (1.f / DVV) - mean * mean;
    const float rstd = rsqrtf(var + 1e-5f);
    const float4 gv = *(const float4*)(vg + gbase);
    const float4 wv = *(const float4*)(lnw + lane * 4);
    const float4 bv = *(const float4*)(lnb + lane * 4);
    float4 res;
    res.x = ((ov.x - mean) * rstd * wv.x + bv.x) * (gv.x / (1.f + expf(-gv.x)));
    res.y = ((ov.y - mean) * rstd * wv.y + bv.y) * (gv.y / (1.f + expf(-gv.y)));
    res.z = ((ov.z - mean) * rstd * wv.z + bv.z) * (gv.z / (1.f + expf(-gv.z)));
    res.w = ((ov.w - mean) * rstd * wv.w + bv.w) * (gv.w / (1.f + expf(-gv.w)));
    ushort4 p;
    p.x = f2h(res.x); p.y = f2h(res.y); p.z = f2h(res.z); p.w = f2h(res.w);
    *(ushort4*)(out + obase) = p;
}

extern "C" void kernel_launch(void* const* d_in, const int* in_sizes, int n_in,
                              void* d_out, int out_size, void* d_ws, size_t ws_size,
                              hipStream_t stream)
{
    const float* x     = (const float*)d_in[0];
    const float* mu_x  = (const float*)d_in[1];
    const float* Wx1   = (const float*)d_in[2];
    const float* Wx2   = (const float*)d_in[3];
    const float* xb    = (const float*)d_in[4];
    const float* Wr    = (const float*)d_in[5];
    const float* Wk    = (const float*)d_in[6];
    const float* Wv    = (const float*)d_in[7];
    const float* Wg    = (const float*)d_in[8];
    const float* Ww1   = (const float*)d_in[9];
    const float* Ww2   = (const float*)d_in[10];
    const float* bw2   = (const float*)d_in[11];
    const float* bonus = (const float*)d_in[12];
    const float* lnw   = (const float*)d_in[13];
    const float* lnb   = (const float*)d_in[14];
    const float* Wo    = (const float*)d_in[15];
    float* out = (float*)d_out;
    (void)in_sizes; (void)n_in; (void)out_size; (void)ws_size;

    float* ws = (float*)d_ws;
    // layout (f32 word offsets) — FIXED round-8 overflows:
    //   wlow16 now has its full 262144 words; SentryT16 aliases decB
    //   (dead after scan_pass1), NOT xp.
    unsigned short* Wx1p = (unsigned short*)(ws + 0);         // 256x1024 fp16 = 131072 w
    unsigned short* Ww1p = (unsigned short*)(ws + 131072);    // 128x1024 fp16 = 65536 w
    unsigned short* Ww2p = (unsigned short*)(ws + 196608);    // 512x64 fp16 = 16384 w
    unsigned short* Wb   = (unsigned short*)(ws + 212992);    // packed weights = 2097152 w
    float* xp     = ws + 2310144;                             // 4096x256 f32 = 1048576 w
    unsigned short* wlow16 = (unsigned short*)(ws + 3358720); // 4096x128 fp16 = 262144 w
    float* insB   = ws + 3620864;                             // 5 fp16 slots x 2097152 w
    float* rkB    = ws + 14106624;                            // 4097x1024 f32 (incl slack)
    float* vgB    = ws + 18301952;                            // 4097x2048 f32 (incl slack)
    float* decB   = ws + 26692608;                            // 4097x512 f32 (incl slack)
    // total: 28790272 words (~115 MB)

    unsigned short* insb = (unsigned short*)insB;             // slot n: insb + n*4194304
    unsigned short* Wrb  = Wb;                                // rows 0-1023 = [Wr;Wk]
    unsigned short* Wvb  = Wb + 1048576;                      // rows 0-2047 = [Wv;Wg]
    unsigned short* Wob  = Wb + 3145728;
    unsigned short* xl16 = (unsigned short*)rkB;              // dead before rk GEMM writes
    // scan-time aliases over consumed regions (stream-ordered, verified):
    float*          o       = insB;                                   // slots 0,1 (in_r/in_w consumed)
    unsigned short* rt16    = insb + 2ul * 4194304;                   // slot 2 (in_k consumed)
    float*          Sloc    = insB + 3ul * 2097152;                   // slots 3+4 (in_v/in_g consumed)
    float*          Dtot    = (float*)wlow16;                         // dead after dec GEMM
    unsigned short* SentryT16 = (unsigned short*)decB;                // dead after scan_pass1
    unsigned short* gatedb  = (unsigned short*)(insB + 3ul * 2097152);// slot 3 (Sloc dead after pass2)

    dim3 blk(256);

    prep_kernel<<<dim3(8608), blk, 0, stream>>>(Wr, Wk, Wv, Wg, Wo, Wx1, Ww1, Ww2,
                                                Wb, Wx1p, Ww1p, Ww2p, x, mu_x, xl16);

    // xp = tanh(xl @ Wx1p^T)  [4096 x 256 f32, cols 160.. are zero]
    gemm_mfma_bt<EPI_TANH><<<dim3(32, 2), blk, 0, stream>>>(
        xl16, xl16, 1 << 30, H, Wx1p, H, xp, nullptr, 256, H, nullptr);

    // fused thin-K: in_n = x + delta*(xp_n @ Wx2_n^T + x_bias_n) -> fp16 slot n
    gemm_bt<EPI_LERP><<<dim3(64, 16, 5), blk, 0, stream>>>(
        xp, 256, 0, Wx2, 160, 0, nullptr, insb, H, MTOT, H, 32, x, xb);

    // wlow16 = tanh(in_w16 @ Ww1p^T) fp16  [4096 x 128, cols 64.. zero]
    gemm_mfma_bt<EPI_TANH16><<<dim3(32, 1), blk, 0, stream>>>(
        insb + 1ul * 4194304, insb + 1ul * 4194304, 1 << 30, H, Ww1p, H,
        nullptr, wlow16, 128, H, nullptr);

    // dec = exp(-exp(wlow16 @ Ww2p^T + bw2))  (fp16 MFMA, K=64)
    gemm_mfma_bt<EPI_DEC><<<dim3(32, 4), blk, 0, stream>>>(
        wlow16, wlow16, 1 << 30, 128, Ww2p, 64, decB, nullptr, KDIM, 64, bw2);

    // fused projections: rk = [r|k] (N=1024), vg = [v|g] (N=2048)
    gemm_mfma_bt<EPI_NONE><<<dim3(32, 8), blk, 0, stream>>>(
        insb + 0ul * 4194304, insb + 2ul * 4194304, 512, H, Wrb, H, rkB, nullptr, 1024, H, nullptr);
    gemm_mfma_bt<EPI_NONE><<<dim3(32, 16), blk, 0, stream>>>(
        insb + 3ul * 4194304, insb + 4ul * 4194304, 1024, H, Wvb, H, vgB, nullptr, 2048, H, nullptr);

    // segmented RWKV scan (16 segments, XCD-swizzled)
    scan_pass1<<<dim3(1024), blk, 0, stream>>>(rkB, vgB, decB, bonus, o, rt16, Sloc, Dtot);
    scan_pass2<<<dim3(256), blk, 0, stream>>>(Sloc, Dtot, SentryT16);
    gemm_mfma_corr<<<dim3(1, 2, 120), blk, 0, stream>>>(rt16, SentryT16, o);

    // per-head LN + swish gate -> fp16 gated
    ln_gate_kernel<<<dim3(4096), blk, 0, stream>>>(o, vgB, lnw, lnb, gatedb);

    // out = gated @ Wo^T
    gemm_mfma_bt<EPI_NONE><<<dim3(32, 8), blk, 0, stream>>>(
        gatedb, gatedb, 1 << 30, VDIM, Wob, VDIM, out, nullptr, H, VDIM, nullptr);
}